// Round 14
// baseline (446.761 us; speedup 1.0000x reference)
//
#include <hip/hip_runtime.h>

#define N_NODES 100000
#define N_EDGES 600000
#define DIM 128

#define AGG_BLOCKS  1024
#define EDGE_BLOCKS 2048

typedef __attribute__((ext_vector_type(8))) short short8;   // 8 bf16 (4 VGPRs)
typedef __attribute__((ext_vector_type(4))) float floatx4;  // MFMA C/D frag
typedef unsigned short ushort_t;

#define MFMA(a,b,c) __builtin_amdgcn_mfma_f32_16x16x32_bf16((a),(b),(c),0,0,0)

// Raw barrier WITHOUT vmcnt drain (lgkmcnt(0) = LDS visibility only);
// global prefetch loads stay in flight across it.
__device__ __forceinline__ void bar_sync() {
    asm volatile("s_waitcnt lgkmcnt(0)" ::: "memory");
    __builtin_amdgcn_s_barrier();
    asm volatile("" ::: "memory");
}

__device__ __forceinline__ unsigned short f2bf(float f) {
    unsigned int u = __float_as_uint(f);
    u += 0x7fffu + ((u >> 16) & 1u);   // round-to-nearest-even
    return (unsigned short)(u >> 16);
}

__device__ __forceinline__ short8 pack8(const float4& a, const float4& b) {
    short8 r;
    r[0] = (short)f2bf(a.x); r[1] = (short)f2bf(a.y);
    r[2] = (short)f2bf(a.z); r[3] = (short)f2bf(a.w);
    r[4] = (short)f2bf(b.x); r[5] = (short)f2bf(b.y);
    r[6] = (short)f2bf(b.z); r[7] = (short)f2bf(b.w);
    return r;
}

// bf16 + bf16 -> bf16 (fp32 add internally)
__device__ __forceinline__ short8 addpack_bf(short8 a, short8 b) {
    short8 r;
    #pragma unroll
    for (int i = 0; i < 8; ++i) {
        const float fa = __uint_as_float(((unsigned int)(unsigned short)a[i]) << 16);
        const float fb = __uint_as_float(((unsigned int)(unsigned short)b[i]) << 16);
        r[i] = (short)f2bf(fa + fb);
    }
    return r;
}

__device__ __forceinline__ float mish_f(float v) {
    if (v > 30.0f) return v;
    float t = __expf(v);
    float z = 1.0f + t;
    float z2 = z * z;
    return v * (z2 - 1.0f) / (z2 + 1.0f);
}

// B-fragment of W (row-major [K][128] fp32) for col-tile ct, k-tile kt.
__device__ __forceinline__ short8 load_bfrag(const float* __restrict__ W,
                                             int ct, int kt, int lane) {
    const float* p = W + (size_t)(kt * 32 + (lane >> 4) * 8) * DIM + ct * 16 + (lane & 15);
    short8 r;
    #pragma unroll
    for (int j = 0; j < 8; ++j) r[j] = (short)f2bf(p[(size_t)j * DIM]);
    return r;
}

// ---- split MLP: L1 (MFMA + mish -> s_h) and L2 (MFMA -> nt store) ----
// s_in/s_h: XOR-granule swizzle (granule=16B, phys = g ^ (row&7)).

__device__ __forceinline__ void mlp_l1(
    const ushort_t* __restrict__ s_in_p, ushort_t* __restrict__ s_h_p,
    const short8 (&w1f)[8], float b1v, int wave, int lane)
{
    const int r0 = lane & 15, q = lane >> 4, sw = lane & 7;
    floatx4 acc0 = {0.f,0.f,0.f,0.f}, acc1 = acc0;
    #pragma unroll
    for (int kt = 0; kt < 8; ++kt) {
        const int g = kt * 4 + q;
        short8 a0 = *(const short8*)&s_in_p[r0 * 256 + (g ^ sw) * 8];
        short8 a1 = *(const short8*)&s_in_p[(16 + r0) * 256 + (g ^ sw) * 8];
        acc0 = MFMA(a0, w1f[kt], acc0);
        acc1 = MFMA(a1, w1f[kt], acc1);
    }
    const int colg = wave * 2 + (r0 >> 3);
    const int bq   = r0 & 7;
    #pragma unroll
    for (int i = 0; i < 4; ++i) {
        int row = q * 4 + i;
        s_h_p[row * 128 + (colg ^ (row & 7)) * 8 + bq] = f2bf(mish_f(acc0[i] + b1v));
        row += 16;
        s_h_p[row * 128 + (colg ^ (row & 7)) * 8 + bq] = f2bf(mish_f(acc1[i] + b1v));
    }
}

__device__ __forceinline__ void mlp_l2(
    const ushort_t* __restrict__ s_h_p,
    const short8 (&w2f)[4], float b2v, float* __restrict__ out, int wave, int lane)
{
    const int r0 = lane & 15, q = lane >> 4, sw = lane & 7;
    floatx4 c0 = {0.f,0.f,0.f,0.f}, c1 = c0;
    #pragma unroll
    for (int kt = 0; kt < 4; ++kt) {
        const int g = kt * 4 + q;
        short8 a0 = *(const short8*)&s_h_p[r0 * 128 + (g ^ sw) * 8];
        short8 a1 = *(const short8*)&s_h_p[(16 + r0) * 128 + (g ^ sw) * 8];
        c0 = MFMA(a0, w2f[kt], c0);
        c1 = MFMA(a1, w2f[kt], c1);
    }
    const int col = wave * 16 + r0;
    #pragma unroll
    for (int i = 0; i < 4; ++i) {
        __builtin_nontemporal_store(c0[i] + b2v, &out[(size_t)(q * 4 + i) * DIM + col]);
        __builtin_nontemporal_store(c1[i] + b2v, &out[(size_t)(16 + q * 4 + i) * DIM + col]);
    }
}

// ---------------- utility / CSR construction ----------------

// fused: blocks [0,98) zero deg; blocks [98, 98+6250) convert x -> bf16
__global__ __launch_bounds__(256)
void zero_xbf_kernel(uint4* __restrict__ deg4, int n4,
                     const float* __restrict__ x, ushort_t* __restrict__ x_bf) {
    const int b = blockIdx.x;
    if (b < 98) {
        const int i = b * 256 + threadIdx.x;
        if (i < n4) deg4[i] = make_uint4(0u, 0u, 0u, 0u);
        return;
    }
    const int i = (b - 98) * 256 + threadIdx.x;   // 1.6M threads x 8 elems
    const float* p = x + (size_t)i * 8;
    *(short8*)&x_bf[(size_t)i * 8] = pack8(*(const float4*)p, *(const float4*)(p + 4));
}

__global__ __launch_bounds__(256)
void hist_kernel(const int* __restrict__ dst_idx, int* __restrict__ deg) {
    const int e = blockIdx.x * 256 + threadIdx.x;
    if (e < N_EDGES) atomicAdd(&deg[dst_idx[e]], 1);
}

__global__ __launch_bounds__(1024)
void scan_a(const int* __restrict__ deg, int* __restrict__ tmp, int* __restrict__ partials) {
    __shared__ int sm[1024];
    const int t = threadIdx.x;
    const int i = blockIdx.x * 1024 + t;
    const int v = (i < N_NODES) ? deg[i] : 0;
    sm[t] = v; __syncthreads();
    for (int d = 1; d < 1024; d <<= 1) {
        int u = (t >= d) ? sm[t - d] : 0; __syncthreads();
        sm[t] += u; __syncthreads();
    }
    if (i < N_NODES) tmp[i] = sm[t] - v;          // block-local exclusive
    if (t == 1023) partials[blockIdx.x] = sm[t];
}

__global__ __launch_bounds__(128)
void scan_b(const int* __restrict__ partials, int* __restrict__ poffs) {
    __shared__ int sm[128];
    const int t = threadIdx.x;
    const int v = (t < 98) ? partials[t] : 0;
    sm[t] = v; __syncthreads();
    for (int d = 1; d < 128; d <<= 1) {
        int u = (t >= d) ? sm[t - d] : 0; __syncthreads();
        sm[t] += u; __syncthreads();
    }
    poffs[t] = sm[t] - v;                          // exclusive
}

__global__ __launch_bounds__(1024)
void scan_c(const int* __restrict__ tmp, const int* __restrict__ poffs,
            int* __restrict__ rowptr, int* __restrict__ cursor) {
    const int t = threadIdx.x;
    const int i = blockIdx.x * 1024 + t;
    if (i < N_NODES) {
        const int v = tmp[i] + poffs[blockIdx.x];
        rowptr[i] = v; cursor[i] = v;
    }
    if (i == 0) rowptr[N_NODES] = N_EDGES;
}

__global__ __launch_bounds__(256)
void scatter_kernel(const int* __restrict__ dst_idx, int* __restrict__ cursor,
                    int* __restrict__ perm) {
    const int e = blockIdx.x * 256 + threadIdx.x;
    if (e < N_EDGES) {
        const int pos = atomicAdd(&cursor[dst_idx[e]], 1);
        perm[pos] = e;
    }
}

// ---- fused dispatch: blocks [0,AGG_BLOCKS) = agg gather (latency-bound,
// ---- dispatched first; its edge_attr re-read rides the edge path's L2/L3
// ---- residency: round-13 FETCH showed full absorption). Blocks
// ---- [AGG_BLOCKS,+EDGE_BLOCKS) = edge MLP, single-barrier double-buffered.

__global__ __launch_bounds__(512)
void edge_agg_kernel(const ushort_t* __restrict__ x_bf,
                     const float* __restrict__ edge_attr,
                     const int* __restrict__ src_idx, const int* __restrict__ dst_idx,
                     const int* __restrict__ rowptr, const int* __restrict__ perm,
                     const float* __restrict__ W1, const float* __restrict__ b1,
                     const float* __restrict__ W2, const float* __restrict__ b2,
                     float* __restrict__ e_out, ushort_t* __restrict__ agg_bf)
{
    __shared__ ushort_t s_in[2][32 * 256];   // 32 KB (edge path)
    __shared__ ushort_t s_h[2][32 * 128];    // 16 KB
    const int tid = threadIdx.x;

    if (blockIdx.x < AGG_BLOCKS) {
        // ---- agg path: 32 nodes/block (16 lanes each), 4-deep row ILP ----
        const int sub = tid >> 4;                        // 0..31
        const int ln  = tid & 15;                        // 16 lanes x 32B = row
        for (int grp = blockIdx.x; grp < N_NODES / 32; grp += AGG_BLOCKS) {
            const int g = grp * 32 + sub;
            const int k0 = rowptr[g], k1 = rowptr[g + 1];
            float4 A0 = {0.f,0.f,0.f,0.f}, A1 = A0, B0 = A0, B1 = A0;
            int e0 = 0, e1 = 0, e2 = 0, e3 = 0;          // named regs (rule 20)
            if (k0 < k1)     e0 = perm[k0];
            if (k0 + 1 < k1) e1 = perm[k0 + 1];
            if (k0 + 2 < k1) e2 = perm[k0 + 2];
            if (k0 + 3 < k1) e3 = perm[k0 + 3];
            int k = k0;
            for (; k + 3 < k1; k += 4) {                 // 4 rows in flight
                const float* p0 = edge_attr + (size_t)e0 * DIM + ln * 8;
                const float* p1 = edge_attr + (size_t)e1 * DIM + ln * 8;
                const float* p2 = edge_attr + (size_t)e2 * DIM + ln * 8;
                const float* p3 = edge_attr + (size_t)e3 * DIM + ln * 8;
                const float4 a0 = *(const float4*)p0, a1 = *(const float4*)(p0 + 4);
                const float4 b0 = *(const float4*)p1, b1 = *(const float4*)(p1 + 4);
                const float4 c0 = *(const float4*)p2, c1 = *(const float4*)(p2 + 4);
                const float4 d0 = *(const float4*)p3, d1 = *(const float4*)(p3 + 4);
                if (k + 4 < k1) e0 = perm[k + 4];
                if (k + 5 < k1) e1 = perm[k + 5];
                if (k + 6 < k1) e2 = perm[k + 6];
                if (k + 7 < k1) e3 = perm[k + 7];
                A0.x += a0.x + c0.x; A0.y += a0.y + c0.y; A0.z += a0.z + c0.z; A0.w += a0.w + c0.w;
                A1.x += a1.x + c1.x; A1.y += a1.y + c1.y; A1.z += a1.z + c1.z; A1.w += a1.w + c1.w;
                B0.x += b0.x + d0.x; B0.y += b0.y + d0.y; B0.z += b0.z + d0.z; B0.w += b0.w + d0.w;
                B1.x += b1.x + d1.x; B1.y += b1.y + d1.y; B1.z += b1.z + d1.z; B1.w += b1.w + d1.w;
            }
            const int rem = k1 - k;                      // 0..3 tail = e0,e1,e2
            if (rem > 0) {
                const float* p = edge_attr + (size_t)e0 * DIM + ln * 8;
                const float4 v0 = *(const float4*)p, v1 = *(const float4*)(p + 4);
                A0.x += v0.x; A0.y += v0.y; A0.z += v0.z; A0.w += v0.w;
                A1.x += v1.x; A1.y += v1.y; A1.z += v1.z; A1.w += v1.w;
            }
            if (rem > 1) {
                const float* p = edge_attr + (size_t)e1 * DIM + ln * 8;
                const float4 v0 = *(const float4*)p, v1 = *(const float4*)(p + 4);
                B0.x += v0.x; B0.y += v0.y; B0.z += v0.z; B0.w += v0.w;
                B1.x += v1.x; B1.y += v1.y; B1.z += v1.z; B1.w += v1.w;
            }
            if (rem > 2) {
                const float* p = edge_attr + (size_t)e2 * DIM + ln * 8;
                const float4 v0 = *(const float4*)p, v1 = *(const float4*)(p + 4);
                A0.x += v0.x; A0.y += v0.y; A0.z += v0.z; A0.w += v0.w;
                A1.x += v1.x; A1.y += v1.y; A1.z += v1.z; A1.w += v1.w;
            }
            A0.x += B0.x; A0.y += B0.y; A0.z += B0.z; A0.w += B0.w;
            A1.x += B1.x; A1.y += B1.y; A1.z += B1.z; A1.w += B1.w;
            *(short8*)&agg_bf[(size_t)g * DIM + ln * 8] = pack8(A0, A1);
        }
        return;
    }

    // ---- edge path: single-barrier, double-buffered pipeline ----
    // Iter (tile t, parity p):  L1(s_in[p]) ; mish->s_h[p] ; pack(t+1)->s_in[p^1] ;
    // issue loads(t+2) ; bar ; L2(s_h[p]).  Hazards: s_in[p^1] last read iter t-1
    // (pre its barrier); s_h[p] last read iter t-2 (pre iter t-1 barrier). Safe
    // with ONE barrier by per-wave program order.
    const int wave = tid >> 6, lane = tid & 63;

    short8 w1f[8], w2f[4];
    const float b1v = b1[wave * 16 + (lane & 15)];
    const float b2v = b2[wave * 16 + (lane & 15)];
    #pragma unroll
    for (int kt = 0; kt < 8; ++kt) w1f[kt] = load_bfrag(W1, wave, kt, lane);
    #pragma unroll
    for (int kt = 0; kt < 4; ++kt) w2f[kt] = load_bfrag(W2, wave, kt, lane);

    const int r = tid >> 4, gq = tid & 15, swr = r & 7;
    const int woff_ea = r * 256 + (gq ^ swr) * 8;
    const int woff_x  = r * 256 + ((16 + gq) ^ swr) * 8;

    const int ntiles = N_EDGES / 32;   // 18750
    int t = blockIdx.x - AGG_BLOCKS;

    float4 ea0, ea1;
    short8 xsb, xdb;
    {   // rows(t) -> regs
        const int k = t * 32 + r;
        const int s = src_idx[k], d = dst_idx[k];
        const float* pe = edge_attr + (size_t)k * DIM + gq * 8;
        ea0 = *(const float4*)pe; ea1 = *(const float4*)(pe + 4);
        xsb = *(const short8*)&x_bf[(size_t)s * DIM + gq * 8];
        xdb = *(const short8*)&x_bf[(size_t)d * DIM + gq * 8];
    }
    // pack rows(t) -> s_in[0]
    *(short8*)&s_in[0][woff_ea] = pack8(ea0, ea1);
    *(short8*)&s_in[0][woff_x]  = addpack_bf(xsb, xdb);
    {   // issue rows(t+G) -> regs (in flight across the barrier)
        const int tn = t + EDGE_BLOCKS;
        if (tn < ntiles) {
            const int k = tn * 32 + r;
            const int s = src_idx[k], d = dst_idx[k];
            const float* pe = edge_attr + (size_t)k * DIM + gq * 8;
            ea0 = *(const float4*)pe; ea1 = *(const float4*)(pe + 4);
            xsb = *(const short8*)&x_bf[(size_t)s * DIM + gq * 8];
            xdb = *(const short8*)&x_bf[(size_t)d * DIM + gq * 8];
        }
    }
    bar_sync();

    int p = 0;
    for (; t < ntiles; t += EDGE_BLOCKS, p ^= 1) {
        mlp_l1(&s_in[p][0], &s_h[p][0], w1f, b1v, wave, lane);

        const int tn = t + EDGE_BLOCKS;
        if (tn < ntiles) {
            // pack rows(tn) (consumes prefetch regs) -> alternate buffer
            *(short8*)&s_in[p ^ 1][woff_ea] = pack8(ea0, ea1);
            *(short8*)&s_in[p ^ 1][woff_x]  = addpack_bf(xsb, xdb);
            const int tnn = tn + EDGE_BLOCKS;
            if (tnn < ntiles) {                  // issue rows(tnn)
                const int k = tnn * 32 + r;
                const int s = src_idx[k], d = dst_idx[k];
                const float* pe = edge_attr + (size_t)k * DIM + gq * 8;
                ea0 = *(const float4*)pe; ea1 = *(const float4*)(pe + 4);
                xsb = *(const short8*)&x_bf[(size_t)s * DIM + gq * 8];
                xdb = *(const short8*)&x_bf[(size_t)d * DIM + gq * 8];
            }
        }
        bar_sync();   // single barrier per tile
        mlp_l2(&s_h[p][0], w2f, b2v, e_out + (size_t)t * 32 * DIM, wave, lane);
    }
}

__global__ __launch_bounds__(512)
void node_kernel(const float* __restrict__ x, const ushort_t* __restrict__ agg_bf,
                 const float* __restrict__ W1, const float* __restrict__ b1,
                 const float* __restrict__ W2, const float* __restrict__ b2,
                 float* __restrict__ x_out)
{
    __shared__ ushort_t s_in[2][32 * 256];
    __shared__ ushort_t s_h[2][32 * 128];
    const int tid = threadIdx.x, wave = tid >> 6, lane = tid & 63;

    short8 w1f[8], w2f[4];
    const float b1v = b1[wave * 16 + (lane & 15)];
    const float b2v = b2[wave * 16 + (lane & 15)];
    #pragma unroll
    for (int kt = 0; kt < 8; ++kt) w1f[kt] = load_bfrag(W1, wave, kt, lane);
    #pragma unroll
    for (int kt = 0; kt < 4; ++kt) w2f[kt] = load_bfrag(W2, wave, kt, lane);

    const int r = tid >> 4, gq = tid & 15, swr = r & 7;
    const int woff_x = r * 256 + (gq ^ swr) * 8;
    const int woff_a = r * 256 + ((16 + gq) ^ swr) * 8;

    const int ntiles = N_NODES / 32;   // 3125
    int t = blockIdx.x;

    float4 xv0, xv1;
    short8 ag;
    {
        const float* px = x + (size_t)(t * 32 + r) * DIM + gq * 8;
        xv0 = *(const float4*)px; xv1 = *(const float4*)(px + 4);
        ag  = *(const short8*)&agg_bf[(size_t)(t * 32 + r) * DIM + gq * 8];
    }
    *(short8*)&s_in[0][woff_x] = pack8(xv0, xv1);
    *(short8*)&s_in[0][woff_a] = ag;
    {
        const int tn = t + (int)gridDim.x;
        if (tn < ntiles) {
            const float* px = x + (size_t)(tn * 32 + r) * DIM + gq * 8;
            xv0 = *(const float4*)px; xv1 = *(const float4*)(px + 4);
            ag  = *(const short8*)&agg_bf[(size_t)(tn * 32 + r) * DIM + gq * 8];
        }
    }
    bar_sync();

    int p = 0;
    const int G = gridDim.x;
    for (; t < ntiles; t += G, p ^= 1) {
        mlp_l1(&s_in[p][0], &s_h[p][0], w1f, b1v, wave, lane);
        const int tn = t + G;
        if (tn < ntiles) {
            *(short8*)&s_in[p ^ 1][woff_x] = pack8(xv0, xv1);
            *(short8*)&s_in[p ^ 1][woff_a] = ag;
            const int tnn = tn + G;
            if (tnn < ntiles) {
                const float* px = x + (size_t)(tnn * 32 + r) * DIM + gq * 8;
                xv0 = *(const float4*)px; xv1 = *(const float4*)(px + 4);
                ag  = *(const short8*)&agg_bf[(size_t)(tnn * 32 + r) * DIM + gq * 8];
            }
        }
        bar_sync();
        mlp_l2(&s_h[p][0], w2f, b2v, x_out + (size_t)t * 32 * DIM, wave, lane);
    }
}

extern "C" void kernel_launch(void* const* d_in, const int* in_sizes, int n_in,
                              void* d_out, int out_size, void* d_ws, size_t ws_size,
                              hipStream_t stream)
{
    const float* x         = (const float*)d_in[0];
    const float* edge_attr = (const float*)d_in[1];
    const int*   ei        = (const int*)d_in[2];   // [2, E]: src row then dst row
    const float* eW1 = (const float*)d_in[3];
    const float* eb1 = (const float*)d_in[4];
    const float* eW2 = (const float*)d_in[5];
    const float* eb2 = (const float*)d_in[6];
    const float* nW1 = (const float*)d_in[7];
    const float* nb1 = (const float*)d_in[8];
    const float* nW2 = (const float*)d_in[9];
    const float* nb2 = (const float*)d_in[10];

    float* out   = (float*)d_out;
    float* x_out = out;                             // [N, 128]
    float* e_out = out + (size_t)N_NODES * DIM;     // [E, 128]

    const int* src_idx = ei;
    const int* dst_idx = ei + N_EDGES;

    // workspace (ints): deg | tmp | rowptr | cursor | perm | partials | poffs | agg_bf
    int* wsi      = (int*)d_ws;
    int* deg      = wsi;                   // 100352
    int* tmp      = wsi + 100352;          // 100352
    int* rowptr   = wsi + 200704;          // 100352 (N+1 used)
    int* cursor   = wsi + 301056;          // 100352
    int* perm     = wsi + 401408;          // 600000
    int* partials = wsi + 1001408;         // 128
    int* poffs    = wsi + 1001536;         // 128
    ushort_t* agg_bf = (ushort_t*)(wsi + 1001664);  // 12.8M bf16 = 25.6 MB

    // x_bf lives in the x_out output region (25.6 of 51.2 MB): read only by
    // edge_agg_kernel, which runs BEFORE node_kernel overwrites x_out.
    ushort_t* x_bf = (ushort_t*)x_out;

    const int egrid = (N_EDGES + 255) / 256;
    zero_xbf_kernel<<<dim3(98 + 6250), dim3(256), 0, stream>>>(
        (uint4*)deg, 25088, x, x_bf);
    hist_kernel   <<<dim3(egrid), dim3(256),  0, stream>>>(dst_idx, deg);
    scan_a        <<<dim3(98),    dim3(1024), 0, stream>>>(deg, tmp, partials);
    scan_b        <<<dim3(1),     dim3(128),  0, stream>>>(partials, poffs);
    scan_c        <<<dim3(98),    dim3(1024), 0, stream>>>(tmp, poffs, rowptr, cursor);
    scatter_kernel<<<dim3(egrid), dim3(256),  0, stream>>>(dst_idx, cursor, perm);

    edge_agg_kernel<<<dim3(AGG_BLOCKS + EDGE_BLOCKS), dim3(512), 0, stream>>>(
        x_bf, edge_attr, src_idx, dst_idx, rowptr, perm,
        eW1, eb1, eW2, eb2, e_out, agg_bf);

    node_kernel<<<dim3(2048), dim3(512), 0, stream>>>(
        x, agg_bf, nW1, nb1, nW2, nb2, x_out);
}

// Round 15
// 356.095 us; speedup vs baseline: 1.2546x; 1.2546x over previous
//
#include <hip/hip_runtime.h>

#define N_NODES 100000
#define N_EDGES 600000
#define DIM 128

typedef __attribute__((ext_vector_type(8))) short short8;   // 8 bf16 (4 VGPRs)
typedef __attribute__((ext_vector_type(4))) float floatx4;  // MFMA C/D frag
typedef unsigned short ushort_t;

#define MFMA(a,b,c) __builtin_amdgcn_mfma_f32_16x16x32_bf16((a),(b),(c),0,0,0)

// Raw barrier WITHOUT vmcnt drain: __syncthreads makes the compiler emit
// s_waitcnt vmcnt(0) before s_barrier, draining cross-barrier prefetch.
// lgkmcnt(0) suffices for cross-wave LDS visibility.
__device__ __forceinline__ void bar_sync() {
    asm volatile("s_waitcnt lgkmcnt(0)" ::: "memory");
    __builtin_amdgcn_s_barrier();
    asm volatile("" ::: "memory");
}

__device__ __forceinline__ unsigned short f2bf(float f) {
    unsigned int u = __float_as_uint(f);
    u += 0x7fffu + ((u >> 16) & 1u);   // round-to-nearest-even
    return (unsigned short)(u >> 16);
}

__device__ __forceinline__ short8 pack8(const float4& a, const float4& b) {
    short8 r;
    r[0] = (short)f2bf(a.x); r[1] = (short)f2bf(a.y);
    r[2] = (short)f2bf(a.z); r[3] = (short)f2bf(a.w);
    r[4] = (short)f2bf(b.x); r[5] = (short)f2bf(b.y);
    r[6] = (short)f2bf(b.z); r[7] = (short)f2bf(b.w);
    return r;
}

// bf16 + bf16 -> bf16 (fp32 add internally)
__device__ __forceinline__ short8 addpack_bf(short8 a, short8 b) {
    short8 r;
    #pragma unroll
    for (int i = 0; i < 8; ++i) {
        const float fa = __uint_as_float(((unsigned int)(unsigned short)a[i]) << 16);
        const float fb = __uint_as_float(((unsigned int)(unsigned short)b[i]) << 16);
        r[i] = (short)f2bf(fa + fb);
    }
    return r;
}

__device__ __forceinline__ float mish_f(float v) {
    if (v > 30.0f) return v;
    float t = __expf(v);
    float z = 1.0f + t;
    float z2 = z * z;
    return v * (z2 - 1.0f) / (z2 + 1.0f);
}

// B-fragment of W (row-major [K][128] fp32) for col-tile ct, k-tile kt.
__device__ __forceinline__ short8 load_bfrag(const float* __restrict__ W,
                                             int ct, int kt, int lane) {
    const float* p = W + (size_t)(kt * 32 + (lane >> 4) * 8) * DIM + ct * 16 + (lane & 15);
    short8 r;
    #pragma unroll
    for (int j = 0; j < 8; ++j) r[j] = (short)f2bf(p[(size_t)j * DIM]);
    return r;
}

// MLP compute on a staged 32-row tile. 8 waves; wave w owns cols [16w,16w+16).
// s_in/s_h: XOR-granule swizzle (granule=16B, phys = g ^ (row&7)).
__device__ __forceinline__ void mlp_core(
    const ushort_t* __restrict__ s_in, ushort_t* __restrict__ s_h,
    const short8 (&w1f)[8], const short8 (&w2f)[4],
    float b1v, float b2v, float* __restrict__ out, int wave, int lane)
{
    const int r0 = lane & 15, q = lane >> 4, sw = lane & 7;

    floatx4 acc0 = {0.f,0.f,0.f,0.f}, acc1 = acc0;
    #pragma unroll
    for (int kt = 0; kt < 8; ++kt) {
        const int g = kt * 4 + q;
        short8 a0 = *(const short8*)&s_in[r0 * 256 + (g ^ sw) * 8];
        short8 a1 = *(const short8*)&s_in[(16 + r0) * 256 + (g ^ sw) * 8];
        acc0 = MFMA(a0, w1f[kt], acc0);
        acc1 = MFMA(a1, w1f[kt], acc1);
    }

    const int colg = wave * 2 + (r0 >> 3);   // 8-col granule index of our column
    const int bq   = r0 & 7;
    #pragma unroll
    for (int i = 0; i < 4; ++i) {
        int row = q * 4 + i;
        s_h[row * 128 + (colg ^ (row & 7)) * 8 + bq] = f2bf(mish_f(acc0[i] + b1v));
        row += 16;
        s_h[row * 128 + (colg ^ (row & 7)) * 8 + bq] = f2bf(mish_f(acc1[i] + b1v));
    }
    bar_sync();   // B2: s_h visible; in-flight global prefetch NOT drained

    floatx4 c0 = {0.f,0.f,0.f,0.f}, c1 = c0;
    #pragma unroll
    for (int kt = 0; kt < 4; ++kt) {
        const int g = kt * 4 + q;
        short8 a0 = *(const short8*)&s_h[r0 * 128 + (g ^ sw) * 8];
        short8 a1 = *(const short8*)&s_h[(16 + r0) * 128 + (g ^ sw) * 8];
        c0 = MFMA(a0, w2f[kt], c0);
        c1 = MFMA(a1, w2f[kt], c1);
    }

    const int col = wave * 16 + r0;
    #pragma unroll
    for (int i = 0; i < 4; ++i) {
        __builtin_nontemporal_store(c0[i] + b2v, &out[(size_t)(q * 4 + i) * DIM + col]);
        __builtin_nontemporal_store(c1[i] + b2v, &out[(size_t)(16 + q * 4 + i) * DIM + col]);
    }
}

// ---------------- utility / CSR construction ----------------

// fused: blocks [0,98) zero deg; blocks [98, 98+6250) convert x -> bf16
__global__ __launch_bounds__(256)
void zero_xbf_kernel(uint4* __restrict__ deg4, int n4,
                     const float* __restrict__ x, ushort_t* __restrict__ x_bf) {
    const int b = blockIdx.x;
    if (b < 98) {
        const int i = b * 256 + threadIdx.x;
        if (i < n4) deg4[i] = make_uint4(0u, 0u, 0u, 0u);
        return;
    }
    const int i = (b - 98) * 256 + threadIdx.x;   // 1.6M threads x 8 elems
    const float* p = x + (size_t)i * 8;
    *(short8*)&x_bf[(size_t)i * 8] = pack8(*(const float4*)p, *(const float4*)(p + 4));
}

__global__ __launch_bounds__(256)
void hist_kernel(const int* __restrict__ dst_idx, int* __restrict__ deg) {
    const int e = blockIdx.x * 256 + threadIdx.x;
    if (e < N_EDGES) atomicAdd(&deg[dst_idx[e]], 1);
}

__global__ __launch_bounds__(1024)
void scan_a(const int* __restrict__ deg, int* __restrict__ tmp, int* __restrict__ partials) {
    __shared__ int sm[1024];
    const int t = threadIdx.x;
    const int i = blockIdx.x * 1024 + t;
    const int v = (i < N_NODES) ? deg[i] : 0;
    sm[t] = v; __syncthreads();
    for (int d = 1; d < 1024; d <<= 1) {
        int u = (t >= d) ? sm[t - d] : 0; __syncthreads();
        sm[t] += u; __syncthreads();
    }
    if (i < N_NODES) tmp[i] = sm[t] - v;          // block-local exclusive
    if (t == 1023) partials[blockIdx.x] = sm[t];
}

// scan_c now also does scan_b's job: each block redundantly scans the 98
// partials in LDS (trivial) -> one fewer dispatch + serialization point.
__global__ __launch_bounds__(1024)
void scan_c(const int* __restrict__ tmp, const int* __restrict__ partials,
            int* __restrict__ rowptr, int* __restrict__ cursor) {
    __shared__ int sm[128];
    const int t = threadIdx.x;
    if (t < 128) sm[t] = (t < 98) ? partials[t] : 0;
    __syncthreads();
    for (int d = 1; d < 128; d <<= 1) {
        int u = 0;
        if (t < 128 && t >= d) u = sm[t - d];
        __syncthreads();
        if (t < 128) sm[t] += u;
        __syncthreads();
    }
    const int poff = (blockIdx.x == 0) ? 0 : sm[blockIdx.x - 1];  // exclusive
    const int i = blockIdx.x * 1024 + t;
    if (i < N_NODES) {
        const int v = tmp[i] + poff;
        rowptr[i] = v; cursor[i] = v;
    }
    if (i == 0) rowptr[N_NODES] = N_EDGES;
}

__global__ __launch_bounds__(256)
void scatter_kernel(const int* __restrict__ dst_idx, int* __restrict__ cursor,
                    int* __restrict__ perm) {
    const int e = blockIdx.x * 256 + threadIdx.x;
    if (e < N_EDGES) {
        const int pos = atomicAdd(&cursor[dst_idx[e]], 1);
        perm[pos] = e;
    }
}

// ------- agg gather: 16-lane group per node, 4-deep row ILP, bf16 out -------

__global__ __launch_bounds__(256)
void agg_kernel(const float* __restrict__ edge_attr, const int* __restrict__ rowptr,
                const int* __restrict__ perm, ushort_t* __restrict__ agg_bf) {
    const int g  = (blockIdx.x << 4) + (threadIdx.x >> 4);   // node id (16/block)
    const int ln = threadIdx.x & 15;                         // 16 lanes x 32B = row
    const int k0 = rowptr[g], k1 = rowptr[g + 1];
    float4 A0 = {0.f,0.f,0.f,0.f}, A1 = A0, B0 = A0, B1 = A0;
    int e0 = 0, e1 = 0, e2 = 0, e3 = 0;               // named regs (rule 20)
    if (k0 < k1)     e0 = perm[k0];
    if (k0 + 1 < k1) e1 = perm[k0 + 1];
    if (k0 + 2 < k1) e2 = perm[k0 + 2];
    if (k0 + 3 < k1) e3 = perm[k0 + 3];
    int k = k0;
    for (; k + 3 < k1; k += 4) {                      // 4 rows in flight
        const float* p0 = edge_attr + (size_t)e0 * DIM + ln * 8;
        const float* p1 = edge_attr + (size_t)e1 * DIM + ln * 8;
        const float* p2 = edge_attr + (size_t)e2 * DIM + ln * 8;
        const float* p3 = edge_attr + (size_t)e3 * DIM + ln * 8;
        const float4 a0 = *(const float4*)p0, a1 = *(const float4*)(p0 + 4);
        const float4 b0 = *(const float4*)p1, b1 = *(const float4*)(p1 + 4);
        const float4 c0 = *(const float4*)p2, c1 = *(const float4*)(p2 + 4);
        const float4 d0 = *(const float4*)p3, d1 = *(const float4*)(p3 + 4);
        if (k + 4 < k1) e0 = perm[k + 4];
        if (k + 5 < k1) e1 = perm[k + 5];
        if (k + 6 < k1) e2 = perm[k + 6];
        if (k + 7 < k1) e3 = perm[k + 7];
        A0.x += a0.x + c0.x; A0.y += a0.y + c0.y; A0.z += a0.z + c0.z; A0.w += a0.w + c0.w;
        A1.x += a1.x + c1.x; A1.y += a1.y + c1.y; A1.z += a1.z + c1.z; A1.w += a1.w + c1.w;
        B0.x += b0.x + d0.x; B0.y += b0.y + d0.y; B0.z += b0.z + d0.z; B0.w += b0.w + d0.w;
        B1.x += b1.x + d1.x; B1.y += b1.y + d1.y; B1.z += b1.z + d1.z; B1.w += b1.w + d1.w;
    }
    const int rem = k1 - k;                           // 0..3 tail rows = e0,e1,e2
    if (rem > 0) {
        const float* p = edge_attr + (size_t)e0 * DIM + ln * 8;
        const float4 v0 = *(const float4*)p, v1 = *(const float4*)(p + 4);
        A0.x += v0.x; A0.y += v0.y; A0.z += v0.z; A0.w += v0.w;
        A1.x += v1.x; A1.y += v1.y; A1.z += v1.z; A1.w += v1.w;
    }
    if (rem > 1) {
        const float* p = edge_attr + (size_t)e1 * DIM + ln * 8;
        const float4 v0 = *(const float4*)p, v1 = *(const float4*)(p + 4);
        B0.x += v0.x; B0.y += v0.y; B0.z += v0.z; B0.w += v0.w;
        B1.x += v1.x; B1.y += v1.y; B1.z += v1.z; B1.w += v1.w;
    }
    if (rem > 2) {
        const float* p = edge_attr + (size_t)e2 * DIM + ln * 8;
        const float4 v0 = *(const float4*)p, v1 = *(const float4*)(p + 4);
        A0.x += v0.x; A0.y += v0.y; A0.z += v0.z; A0.w += v0.w;
        A1.x += v1.x; A1.y += v1.y; A1.z += v1.z; A1.w += v1.w;
    }
    A0.x += B0.x; A0.y += B0.y; A0.z += B0.z; A0.w += B0.w;
    A1.x += B1.x; A1.y += B1.y; A1.z += B1.z; A1.w += B1.w;
    *(short8*)&agg_bf[(size_t)g * DIM + ln * 8] = pack8(A0, A1);
}

// ---------------- main MLP kernels (512 threads, 8 waves) ----------------
// VGPR discipline (measured): <=64 VGPR -> ~40% occ (fast); 65+ -> 23% occ
// (+45% time, r8/r10/r14); forced-32 -> spill disaster (r9). 24KB LDS; the
// round-12 structure is the measured optimum of this landscape.

__global__ __launch_bounds__(512)
void edge_kernel(const ushort_t* __restrict__ x_bf, const float* __restrict__ edge_attr,
                 const int* __restrict__ src_idx, const int* __restrict__ dst_idx,
                 const float* __restrict__ W1, const float* __restrict__ b1,
                 const float* __restrict__ W2, const float* __restrict__ b2,
                 float* __restrict__ e_out)
{
    __shared__ ushort_t s_in[32 * 256];   // 16 KB
    __shared__ ushort_t s_h[32 * 128];    // 8 KB
    const int tid = threadIdx.x, wave = tid >> 6, lane = tid & 63;

    short8 w1f[8], w2f[4];
    const float b1v = b1[wave * 16 + (lane & 15)];
    const float b2v = b2[wave * 16 + (lane & 15)];
    #pragma unroll
    for (int kt = 0; kt < 8; ++kt) w1f[kt] = load_bfrag(W1, wave, kt, lane);
    #pragma unroll
    for (int kt = 0; kt < 4; ++kt) w2f[kt] = load_bfrag(W2, wave, kt, lane);

    const int r = tid >> 4, gq = tid & 15, swr = r & 7;
    ushort_t* w_ea = &s_in[r * 256 + (gq ^ swr) * 8];
    ushort_t* w_x  = &s_in[r * 256 + ((16 + gq) ^ swr) * 8];

    const int ntiles = N_EDGES / 32;   // 18750
    int t = blockIdx.x;
    float4 ea0, ea1;
    short8 xsb, xdb;
    if (t < ntiles) {                                    // prologue loads (tile t)
        const int k = t * 32 + r;
        const int s = src_idx[k], d = dst_idx[k];
        const float* pe = edge_attr + (size_t)k * DIM + gq * 8;
        ea0 = *(const float4*)pe; ea1 = *(const float4*)(pe + 4);
        xsb = *(const short8*)&x_bf[(size_t)s * DIM + gq * 8];
        xdb = *(const short8*)&x_bf[(size_t)d * DIM + gq * 8];
    }
    for (; t < ntiles; t += gridDim.x) {
        // stage current tile: regs -> LDS (prev iter's s_in readers done pre-B2)
        *(short8*)w_ea = pack8(ea0, ea1);
        *(short8*)w_x  = addpack_bf(xsb, xdb);

        const int tn = t + gridDim.x;
        const bool more = tn < ntiles;                   // block-uniform
        int sN = 0, dN = 0;
        if (more) {
            // ea(t+G): sequential HBM stream, no index dep -> issue PRE-B1,
            // gets the entire tile (~900+ cyc) of coverage before consumption
            const float* pe = edge_attr + (size_t)(tn * 32 + r) * DIM + gq * 8;
            ea0 = *(const float4*)pe; ea1 = *(const float4*)(pe + 4);
            const int k = tn * 32 + r;
            sN = src_idx[k]; dN = dst_idx[k];            // idx also pre-B1
        }
        bar_sync();                                      // B1: staging visible
        if (more) {                                      // L3-hot gathers post-B1
            xsb = *(const short8*)&x_bf[(size_t)sN * DIM + gq * 8];
            xdb = *(const short8*)&x_bf[(size_t)dN * DIM + gq * 8];
        }
        mlp_core(s_in, s_h, w1f, w2f, b1v, b2v,
                 e_out + (size_t)t * 32 * DIM, wave, lane);
    }
}

__global__ __launch_bounds__(512)
void node_kernel(const float* __restrict__ x, const ushort_t* __restrict__ agg_bf,
                 const float* __restrict__ W1, const float* __restrict__ b1,
                 const float* __restrict__ W2, const float* __restrict__ b2,
                 float* __restrict__ x_out)
{
    __shared__ ushort_t s_in[32 * 256];
    __shared__ ushort_t s_h[32 * 128];
    const int tid = threadIdx.x, wave = tid >> 6, lane = tid & 63;

    short8 w1f[8], w2f[4];
    const float b1v = b1[wave * 16 + (lane & 15)];
    const float b2v = b2[wave * 16 + (lane & 15)];
    #pragma unroll
    for (int kt = 0; kt < 8; ++kt) w1f[kt] = load_bfrag(W1, wave, kt, lane);
    #pragma unroll
    for (int kt = 0; kt < 4; ++kt) w2f[kt] = load_bfrag(W2, wave, kt, lane);

    const int r = tid >> 4, gq = tid & 15, swr = r & 7;
    ushort_t* w_xp = &s_in[r * 256 + (gq ^ swr) * 8];
    ushort_t* w_ag = &s_in[r * 256 + ((16 + gq) ^ swr) * 8];

    const int ntiles = N_NODES / 32;   // 3125
    int t = blockIdx.x;
    float4 xv0, xv1;
    short8 ag;
    if (t < ntiles) {
        const float* px = x + (size_t)(t * 32 + r) * DIM + gq * 8;
        xv0 = *(const float4*)px; xv1 = *(const float4*)(px + 4);
        ag  = *(const short8*)&agg_bf[(size_t)(t * 32 + r) * DIM + gq * 8];
    }
    for (; t < ntiles; t += gridDim.x) {
        *(short8*)w_xp = pack8(xv0, xv1);
        *(short8*)w_ag = ag;
        const int tn = t + gridDim.x;
        if (tn < ntiles) {                              // both streams sequential:
            const float* px = x + (size_t)(tn * 32 + r) * DIM + gq * 8;   // issue
            xv0 = *(const float4*)px; xv1 = *(const float4*)(px + 4);     // PRE-B1
            ag  = *(const short8*)&agg_bf[(size_t)(tn * 32 + r) * DIM + gq * 8];
        }
        bar_sync();                                     // B1
        mlp_core(s_in, s_h, w1f, w2f, b1v, b2v,
                 x_out + (size_t)t * 32 * DIM, wave, lane);
    }
}

extern "C" void kernel_launch(void* const* d_in, const int* in_sizes, int n_in,
                              void* d_out, int out_size, void* d_ws, size_t ws_size,
                              hipStream_t stream)
{
    const float* x         = (const float*)d_in[0];
    const float* edge_attr = (const float*)d_in[1];
    const int*   ei        = (const int*)d_in[2];   // [2, E]: src row then dst row
    const float* eW1 = (const float*)d_in[3];
    const float* eb1 = (const float*)d_in[4];
    const float* eW2 = (const float*)d_in[5];
    const float* eb2 = (const float*)d_in[6];
    const float* nW1 = (const float*)d_in[7];
    const float* nb1 = (const float*)d_in[8];
    const float* nW2 = (const float*)d_in[9];
    const float* nb2 = (const float*)d_in[10];

    float* out   = (float*)d_out;
    float* x_out = out;                             // [N, 128]
    float* e_out = out + (size_t)N_NODES * DIM;     // [E, 128]

    const int* src_idx = ei;
    const int* dst_idx = ei + N_EDGES;

    // workspace (ints): deg | tmp | rowptr | cursor | perm | partials | agg_bf
    int* wsi      = (int*)d_ws;
    int* deg      = wsi;                   // 100352
    int* tmp      = wsi + 100352;          // 100352
    int* rowptr   = wsi + 200704;          // 100352 (N+1 used)
    int* cursor   = wsi + 301056;          // 100352
    int* perm     = wsi + 401408;          // 600000
    int* partials = wsi + 1001408;         // 128
    ushort_t* agg_bf = (ushort_t*)(wsi + 1001536);  // 12.8M bf16 = 25.6 MB

    // x_bf lives in the x_out output region (25.6 of 51.2 MB): read only by
    // edge_kernel, which runs BEFORE node_kernel overwrites x_out.
    ushort_t* x_bf = (ushort_t*)x_out;

    const int egrid = (N_EDGES + 255) / 256;
    zero_xbf_kernel<<<dim3(98 + 6250), dim3(256), 0, stream>>>(
        (uint4*)deg, 25088, x, x_bf);
    hist_kernel   <<<dim3(egrid), dim3(256),  0, stream>>>(dst_idx, deg);
    scan_a        <<<dim3(98),    dim3(1024), 0, stream>>>(deg, tmp, partials);
    scan_c        <<<dim3(98),    dim3(1024), 0, stream>>>(tmp, partials, rowptr, cursor);
    scatter_kernel<<<dim3(egrid), dim3(256),  0, stream>>>(dst_idx, cursor, perm);

    agg_kernel<<<dim3(6250), dim3(256), 0, stream>>>(edge_attr, rowptr, perm, agg_bf);

    edge_kernel<<<dim3(2048), dim3(512), 0, stream>>>(
        x_bf, edge_attr, src_idx, dst_idx, eW1, eb1, eW2, eb2, e_out);

    node_kernel<<<dim3(2048), dim3(512), 0, stream>>>(
        x, agg_bf, nW1, nb1, nW2, nb2, x_out);
}

// Round 16
// 345.367 us; speedup vs baseline: 1.2936x; 1.0311x over previous
//
#include <hip/hip_runtime.h>

#define N_NODES 100000
#define N_EDGES 600000
#define DIM 128

typedef __attribute__((ext_vector_type(8))) short short8;   // 8 bf16 (4 VGPRs)
typedef __attribute__((ext_vector_type(4))) float floatx4;  // MFMA C/D frag
typedef unsigned short ushort_t;

#define MFMA(a,b,c) __builtin_amdgcn_mfma_f32_16x16x32_bf16((a),(b),(c),0,0,0)

// Raw barrier WITHOUT vmcnt drain: __syncthreads makes the compiler emit
// s_waitcnt vmcnt(0) before s_barrier, draining cross-barrier prefetch.
// lgkmcnt(0) suffices for cross-wave LDS visibility.
__device__ __forceinline__ void bar_sync() {
    asm volatile("s_waitcnt lgkmcnt(0)" ::: "memory");
    __builtin_amdgcn_s_barrier();
    asm volatile("" ::: "memory");
}

__device__ __forceinline__ unsigned short f2bf(float f) {
    unsigned int u = __float_as_uint(f);
    u += 0x7fffu + ((u >> 16) & 1u);   // round-to-nearest-even
    return (unsigned short)(u >> 16);
}

__device__ __forceinline__ short8 pack8(const float4& a, const float4& b) {
    short8 r;
    r[0] = (short)f2bf(a.x); r[1] = (short)f2bf(a.y);
    r[2] = (short)f2bf(a.z); r[3] = (short)f2bf(a.w);
    r[4] = (short)f2bf(b.x); r[5] = (short)f2bf(b.y);
    r[6] = (short)f2bf(b.z); r[7] = (short)f2bf(b.w);
    return r;
}

// bf16 + bf16 -> bf16 (fp32 add internally)
__device__ __forceinline__ short8 addpack_bf(short8 a, short8 b) {
    short8 r;
    #pragma unroll
    for (int i = 0; i < 8; ++i) {
        const float fa = __uint_as_float(((unsigned int)(unsigned short)a[i]) << 16);
        const float fb = __uint_as_float(((unsigned int)(unsigned short)b[i]) << 16);
        r[i] = (short)f2bf(fa + fb);
    }
    return r;
}

__device__ __forceinline__ float mish_f(float v) {
    if (v > 30.0f) return v;
    float t = __expf(v);
    float z = 1.0f + t;
    float z2 = z * z;
    return v * (z2 - 1.0f) / (z2 + 1.0f);
}

// B-fragment of W (row-major [K][128] fp32) for col-tile ct, k-tile kt.
__device__ __forceinline__ short8 load_bfrag(const float* __restrict__ W,
                                             int ct, int kt, int lane) {
    const float* p = W + (size_t)(kt * 32 + (lane >> 4) * 8) * DIM + ct * 16 + (lane & 15);
    short8 r;
    #pragma unroll
    for (int j = 0; j < 8; ++j) r[j] = (short)f2bf(p[(size_t)j * DIM]);
    return r;
}

// MLP compute on a staged 32-row tile. 8 waves; wave w owns cols [16w,16w+16).
// s_in/s_h: XOR-granule swizzle (granule=16B, phys = g ^ (row&7)).
__device__ __forceinline__ void mlp_core(
    const ushort_t* __restrict__ s_in, ushort_t* __restrict__ s_h,
    const short8 (&w1f)[8], const short8 (&w2f)[4],
    float b1v, float b2v, float* __restrict__ out, int wave, int lane)
{
    const int r0 = lane & 15, q = lane >> 4, sw = lane & 7;

    floatx4 acc0 = {0.f,0.f,0.f,0.f}, acc1 = acc0;
    #pragma unroll
    for (int kt = 0; kt < 8; ++kt) {
        const int g = kt * 4 + q;
        short8 a0 = *(const short8*)&s_in[r0 * 256 + (g ^ sw) * 8];
        short8 a1 = *(const short8*)&s_in[(16 + r0) * 256 + (g ^ sw) * 8];
        acc0 = MFMA(a0, w1f[kt], acc0);
        acc1 = MFMA(a1, w1f[kt], acc1);
    }

    const int colg = wave * 2 + (r0 >> 3);   // 8-col granule index of our column
    const int bq   = r0 & 7;
    #pragma unroll
    for (int i = 0; i < 4; ++i) {
        int row = q * 4 + i;
        s_h[row * 128 + (colg ^ (row & 7)) * 8 + bq] = f2bf(mish_f(acc0[i] + b1v));
        row += 16;
        s_h[row * 128 + (colg ^ (row & 7)) * 8 + bq] = f2bf(mish_f(acc1[i] + b1v));
    }
    bar_sync();   // B2: s_h visible; in-flight global prefetch NOT drained

    floatx4 c0 = {0.f,0.f,0.f,0.f}, c1 = c0;
    #pragma unroll
    for (int kt = 0; kt < 4; ++kt) {
        const int g = kt * 4 + q;
        short8 a0 = *(const short8*)&s_h[r0 * 128 + (g ^ sw) * 8];
        short8 a1 = *(const short8*)&s_h[(16 + r0) * 128 + (g ^ sw) * 8];
        c0 = MFMA(a0, w2f[kt], c0);
        c1 = MFMA(a1, w2f[kt], c1);
    }

    const int col = wave * 16 + r0;
    #pragma unroll
    for (int i = 0; i < 4; ++i) {
        __builtin_nontemporal_store(c0[i] + b2v, &out[(size_t)(q * 4 + i) * DIM + col]);
        __builtin_nontemporal_store(c1[i] + b2v, &out[(size_t)(16 + q * 4 + i) * DIM + col]);
    }
}

// ---------------- utility / CSR construction ----------------

// fused: blocks [0,98) zero deg; blocks [98, 98+6250) convert x -> bf16
__global__ __launch_bounds__(256)
void zero_xbf_kernel(uint4* __restrict__ deg4, int n4,
                     const float* __restrict__ x, ushort_t* __restrict__ x_bf) {
    const int b = blockIdx.x;
    if (b < 98) {
        const int i = b * 256 + threadIdx.x;
        if (i < n4) deg4[i] = make_uint4(0u, 0u, 0u, 0u);
        return;
    }
    const int i = (b - 98) * 256 + threadIdx.x;   // 1.6M threads x 8 elems
    const float* p = x + (size_t)i * 8;
    *(short8*)&x_bf[(size_t)i * 8] = pack8(*(const float4*)p, *(const float4*)(p + 4));
}

__global__ __launch_bounds__(256)
void hist_kernel(const int* __restrict__ dst_idx, int* __restrict__ deg) {
    const int e = blockIdx.x * 256 + threadIdx.x;
    if (e < N_EDGES) atomicAdd(&deg[dst_idx[e]], 1);
}

__global__ __launch_bounds__(1024)
void scan_a(const int* __restrict__ deg, int* __restrict__ tmp, int* __restrict__ partials) {
    __shared__ int sm[1024];
    const int t = threadIdx.x;
    const int i = blockIdx.x * 1024 + t;
    const int v = (i < N_NODES) ? deg[i] : 0;
    sm[t] = v; __syncthreads();
    for (int d = 1; d < 1024; d <<= 1) {
        int u = (t >= d) ? sm[t - d] : 0; __syncthreads();
        sm[t] += u; __syncthreads();
    }
    if (i < N_NODES) tmp[i] = sm[t] - v;          // block-local exclusive
    if (t == 1023) partials[blockIdx.x] = sm[t];
}

// scan_c also does scan_b's job: each block redundantly scans the 98
// partials in LDS (trivial) -> one fewer dispatch + serialization point.
__global__ __launch_bounds__(1024)
void scan_c(const int* __restrict__ tmp, const int* __restrict__ partials,
            int* __restrict__ rowptr, int* __restrict__ cursor) {
    __shared__ int sm[128];
    const int t = threadIdx.x;
    if (t < 128) sm[t] = (t < 98) ? partials[t] : 0;
    __syncthreads();
    for (int d = 1; d < 128; d <<= 1) {
        int u = 0;
        if (t < 128 && t >= d) u = sm[t - d];
        __syncthreads();
        if (t < 128) sm[t] += u;
        __syncthreads();
    }
    const int poff = (blockIdx.x == 0) ? 0 : sm[blockIdx.x - 1];  // exclusive
    const int i = blockIdx.x * 1024 + t;
    if (i < N_NODES) {
        const int v = tmp[i] + poff;
        rowptr[i] = v; cursor[i] = v;
    }
    if (i == 0) rowptr[N_NODES] = N_EDGES;
}

__global__ __launch_bounds__(256)
void scatter_kernel(const int* __restrict__ dst_idx, int* __restrict__ cursor,
                    int* __restrict__ perm) {
    const int e = blockIdx.x * 256 + threadIdx.x;
    if (e < N_EDGES) {
        const int pos = atomicAdd(&cursor[dst_idx[e]], 1);
        perm[pos] = e;
    }
}

// ------- agg gather: 16-lane group per node, 4-deep row ILP, bf16 out -------
// Runs AFTER edge_kernel so its edge_attr gathers hit the L2/L3 residency the
// edge stream just established (nt e_out stores avoid evicting it).

__global__ __launch_bounds__(256)
void agg_kernel(const float* __restrict__ edge_attr, const int* __restrict__ rowptr,
                const int* __restrict__ perm, ushort_t* __restrict__ agg_bf) {
    const int g  = (blockIdx.x << 4) + (threadIdx.x >> 4);   // node id (16/block)
    const int ln = threadIdx.x & 15;                         // 16 lanes x 32B = row
    const int k0 = rowptr[g], k1 = rowptr[g + 1];
    float4 A0 = {0.f,0.f,0.f,0.f}, A1 = A0, B0 = A0, B1 = A0;
    int e0 = 0, e1 = 0, e2 = 0, e3 = 0;               // named regs (rule 20)
    if (k0 < k1)     e0 = perm[k0];
    if (k0 + 1 < k1) e1 = perm[k0 + 1];
    if (k0 + 2 < k1) e2 = perm[k0 + 2];
    if (k0 + 3 < k1) e3 = perm[k0 + 3];
    int k = k0;
    for (; k + 3 < k1; k += 4) {                      // 4 rows in flight
        const float* p0 = edge_attr + (size_t)e0 * DIM + ln * 8;
        const float* p1 = edge_attr + (size_t)e1 * DIM + ln * 8;
        const float* p2 = edge_attr + (size_t)e2 * DIM + ln * 8;
        const float* p3 = edge_attr + (size_t)e3 * DIM + ln * 8;
        const float4 a0 = *(const float4*)p0, a1 = *(const float4*)(p0 + 4);
        const float4 b0 = *(const float4*)p1, b1 = *(const float4*)(p1 + 4);
        const float4 c0 = *(const float4*)p2, c1 = *(const float4*)(p2 + 4);
        const float4 d0 = *(const float4*)p3, d1 = *(const float4*)(p3 + 4);
        if (k + 4 < k1) e0 = perm[k + 4];
        if (k + 5 < k1) e1 = perm[k + 5];
        if (k + 6 < k1) e2 = perm[k + 6];
        if (k + 7 < k1) e3 = perm[k + 7];
        A0.x += a0.x + c0.x; A0.y += a0.y + c0.y; A0.z += a0.z + c0.z; A0.w += a0.w + c0.w;
        A1.x += a1.x + c1.x; A1.y += a1.y + c1.y; A1.z += a1.z + c1.z; A1.w += a1.w + c1.w;
        B0.x += b0.x + d0.x; B0.y += b0.y + d0.y; B0.z += b0.z + d0.z; B0.w += b0.w + d0.w;
        B1.x += b1.x + d1.x; B1.y += b1.y + d1.y; B1.z += b1.z + d1.z; B1.w += b1.w + d1.w;
    }
    const int rem = k1 - k;                           // 0..3 tail rows = e0,e1,e2
    if (rem > 0) {
        const float* p = edge_attr + (size_t)e0 * DIM + ln * 8;
        const float4 v0 = *(const float4*)p, v1 = *(const float4*)(p + 4);
        A0.x += v0.x; A0.y += v0.y; A0.z += v0.z; A0.w += v0.w;
        A1.x += v1.x; A1.y += v1.y; A1.z += v1.z; A1.w += v1.w;
    }
    if (rem > 1) {
        const float* p = edge_attr + (size_t)e1 * DIM + ln * 8;
        const float4 v0 = *(const float4*)p, v1 = *(const float4*)(p + 4);
        B0.x += v0.x; B0.y += v0.y; B0.z += v0.z; B0.w += v0.w;
        B1.x += v1.x; B1.y += v1.y; B1.z += v1.z; B1.w += v1.w;
    }
    if (rem > 2) {
        const float* p = edge_attr + (size_t)e2 * DIM + ln * 8;
        const float4 v0 = *(const float4*)p, v1 = *(const float4*)(p + 4);
        A0.x += v0.x; A0.y += v0.y; A0.z += v0.z; A0.w += v0.w;
        A1.x += v1.x; A1.y += v1.y; A1.z += v1.z; A1.w += v1.w;
    }
    A0.x += B0.x; A0.y += B0.y; A0.z += B0.z; A0.w += B0.w;
    A1.x += B1.x; A1.y += B1.y; A1.z += B1.z; A1.w += B1.w;
    *(short8*)&agg_bf[(size_t)g * DIM + ln * 8] = pack8(A0, A1);
}

// ---------------- main MLP kernels (512 threads, 8 waves) ----------------
// VGPR discipline (measured): <=64 VGPR -> ~40% occ (fast); 65+ -> 23% occ
// (+45% time, r8/r10/r14); forced-32 -> spill disaster (r9). 24KB LDS; the
// round-12/15 structure is the measured optimum of this landscape.

__global__ __launch_bounds__(512)
void edge_kernel(const ushort_t* __restrict__ x_bf, const float* __restrict__ edge_attr,
                 const int* __restrict__ src_idx, const int* __restrict__ dst_idx,
                 const float* __restrict__ W1, const float* __restrict__ b1,
                 const float* __restrict__ W2, const float* __restrict__ b2,
                 float* __restrict__ e_out)
{
    __shared__ ushort_t s_in[32 * 256];   // 16 KB
    __shared__ ushort_t s_h[32 * 128];    // 8 KB
    const int tid = threadIdx.x, wave = tid >> 6, lane = tid & 63;

    short8 w1f[8], w2f[4];
    const float b1v = b1[wave * 16 + (lane & 15)];
    const float b2v = b2[wave * 16 + (lane & 15)];
    #pragma unroll
    for (int kt = 0; kt < 8; ++kt) w1f[kt] = load_bfrag(W1, wave, kt, lane);
    #pragma unroll
    for (int kt = 0; kt < 4; ++kt) w2f[kt] = load_bfrag(W2, wave, kt, lane);

    const int r = tid >> 4, gq = tid & 15, swr = r & 7;
    ushort_t* w_ea = &s_in[r * 256 + (gq ^ swr) * 8];
    ushort_t* w_x  = &s_in[r * 256 + ((16 + gq) ^ swr) * 8];

    const int ntiles = N_EDGES / 32;   // 18750
    int t = blockIdx.x;
    float4 ea0, ea1;
    short8 xsb, xdb;
    if (t < ntiles) {                                    // prologue loads (tile t)
        const int k = t * 32 + r;
        const int s = src_idx[k], d = dst_idx[k];
        const float* pe = edge_attr + (size_t)k * DIM + gq * 8;
        ea0 = *(const float4*)pe; ea1 = *(const float4*)(pe + 4);
        xsb = *(const short8*)&x_bf[(size_t)s * DIM + gq * 8];
        xdb = *(const short8*)&x_bf[(size_t)d * DIM + gq * 8];
    }
    for (; t < ntiles; t += gridDim.x) {
        // stage current tile: regs -> LDS (prev iter's s_in readers done pre-B2)
        *(short8*)w_ea = pack8(ea0, ea1);
        *(short8*)w_x  = addpack_bf(xsb, xdb);

        const int tn = t + gridDim.x;
        const bool more = tn < ntiles;                   // block-uniform
        int sN = 0, dN = 0;
        if (more) {
            // ea(t+G): sequential HBM stream, no index dep -> issue PRE-B1,
            // gets the entire tile (~900+ cyc) of coverage before consumption
            const float* pe = edge_attr + (size_t)(tn * 32 + r) * DIM + gq * 8;
            ea0 = *(const float4*)pe; ea1 = *(const float4*)(pe + 4);
            const int k = tn * 32 + r;
            sN = src_idx[k]; dN = dst_idx[k];            // idx also pre-B1
        }
        bar_sync();                                      // B1: staging visible
        if (more) {                                      // L3-hot gathers post-B1
            xsb = *(const short8*)&x_bf[(size_t)sN * DIM + gq * 8];
            xdb = *(const short8*)&x_bf[(size_t)dN * DIM + gq * 8];
        }
        mlp_core(s_in, s_h, w1f, w2f, b1v, b2v,
                 e_out + (size_t)t * 32 * DIM, wave, lane);
    }
}

__global__ __launch_bounds__(512)
void node_kernel(const float* __restrict__ x, const ushort_t* __restrict__ agg_bf,
                 const float* __restrict__ W1, const float* __restrict__ b1,
                 const float* __restrict__ W2, const float* __restrict__ b2,
                 float* __restrict__ x_out)
{
    __shared__ ushort_t s_in[32 * 256];
    __shared__ ushort_t s_h[32 * 128];
    const int tid = threadIdx.x, wave = tid >> 6, lane = tid & 63;

    short8 w1f[8], w2f[4];
    const float b1v = b1[wave * 16 + (lane & 15)];
    const float b2v = b2[wave * 16 + (lane & 15)];
    #pragma unroll
    for (int kt = 0; kt < 8; ++kt) w1f[kt] = load_bfrag(W1, wave, kt, lane);
    #pragma unroll
    for (int kt = 0; kt < 4; ++kt) w2f[kt] = load_bfrag(W2, wave, kt, lane);

    const int r = tid >> 4, gq = tid & 15, swr = r & 7;
    ushort_t* w_xp = &s_in[r * 256 + (gq ^ swr) * 8];
    ushort_t* w_ag = &s_in[r * 256 + ((16 + gq) ^ swr) * 8];

    const int ntiles = N_NODES / 32;   // 3125
    int t = blockIdx.x;
    float4 xv0, xv1;
    short8 ag;
    if (t < ntiles) {
        const float* px = x + (size_t)(t * 32 + r) * DIM + gq * 8;
        xv0 = *(const float4*)px; xv1 = *(const float4*)(px + 4);
        ag  = *(const short8*)&agg_bf[(size_t)(t * 32 + r) * DIM + gq * 8];
    }
    for (; t < ntiles; t += gridDim.x) {
        *(short8*)w_xp = pack8(xv0, xv1);
        *(short8*)w_ag = ag;
        const int tn = t + gridDim.x;
        if (tn < ntiles) {                              // both streams sequential:
            const float* px = x + (size_t)(tn * 32 + r) * DIM + gq * 8;   // issue
            xv0 = *(const float4*)px; xv1 = *(const float4*)(px + 4);     // PRE-B1
            ag  = *(const short8*)&agg_bf[(size_t)(tn * 32 + r) * DIM + gq * 8];
        }
        bar_sync();                                     // B1
        mlp_core(s_in, s_h, w1f, w2f, b1v, b2v,
                 x_out + (size_t)t * 32 * DIM, wave, lane);
    }
}

extern "C" void kernel_launch(void* const* d_in, const int* in_sizes, int n_in,
                              void* d_out, int out_size, void* d_ws, size_t ws_size,
                              hipStream_t stream)
{
    const float* x         = (const float*)d_in[0];
    const float* edge_attr = (const float*)d_in[1];
    const int*   ei        = (const int*)d_in[2];   // [2, E]: src row then dst row
    const float* eW1 = (const float*)d_in[3];
    const float* eb1 = (const float*)d_in[4];
    const float* eW2 = (const float*)d_in[5];
    const float* eb2 = (const float*)d_in[6];
    const float* nW1 = (const float*)d_in[7];
    const float* nb1 = (const float*)d_in[8];
    const float* nW2 = (const float*)d_in[9];
    const float* nb2 = (const float*)d_in[10];

    float* out   = (float*)d_out;
    float* x_out = out;                             // [N, 128]
    float* e_out = out + (size_t)N_NODES * DIM;     // [E, 128]

    const int* src_idx = ei;
    const int* dst_idx = ei + N_EDGES;

    // workspace (ints): deg | tmp | rowptr | cursor | perm | partials | agg_bf
    int* wsi      = (int*)d_ws;
    int* deg      = wsi;                   // 100352
    int* tmp      = wsi + 100352;          // 100352
    int* rowptr   = wsi + 200704;          // 100352 (N+1 used)
    int* cursor   = wsi + 301056;          // 100352
    int* perm     = wsi + 401408;          // 600000
    int* partials = wsi + 1001408;         // 128
    ushort_t* agg_bf = (ushort_t*)(wsi + 1001536);  // 12.8M bf16 = 25.6 MB

    // x_bf lives in the x_out output region (25.6 of 51.2 MB): read only by
    // edge_kernel, which runs BEFORE node_kernel overwrites x_out.
    ushort_t* x_bf = (ushort_t*)x_out;

    const int egrid = (N_EDGES + 255) / 256;

    // ORDER: edge (streams all of edge_attr through L2/L3) runs BEFORE the
    // CSR chain + agg. edge depends only on x_bf; agg's 307MB gathered
    // re-read of edge_attr then hits the cache residency edge established
    // (round-13 fusion proved full absorption; nt e_out stores don't evict).
    zero_xbf_kernel<<<dim3(98 + 6250), dim3(256), 0, stream>>>(
        (uint4*)deg, 25088, x, x_bf);

    edge_kernel<<<dim3(2048), dim3(512), 0, stream>>>(
        x_bf, edge_attr, src_idx, dst_idx, eW1, eb1, eW2, eb2, e_out);

    hist_kernel   <<<dim3(egrid), dim3(256),  0, stream>>>(dst_idx, deg);
    scan_a        <<<dim3(98),    dim3(1024), 0, stream>>>(deg, tmp, partials);
    scan_c        <<<dim3(98),    dim3(1024), 0, stream>>>(tmp, partials, rowptr, cursor);
    scatter_kernel<<<dim3(egrid), dim3(256),  0, stream>>>(dst_idx, cursor, perm);

    agg_kernel<<<dim3(6250), dim3(256), 0, stream>>>(edge_attr, rowptr, perm, agg_bf);

    node_kernel<<<dim3(2048), dim3(512), 0, stream>>>(
        x, agg_bf, nW1, nb1, nW2, nb2, x_out);
}

// Round 17
// 332.460 us; speedup vs baseline: 1.3438x; 1.0388x over previous
//
#include <hip/hip_runtime.h>

#define N_NODES 100000
#define N_EDGES 600000
#define DIM 128

#define EDGE_BLOCKS 2048
#define HIST_BLOCKS 1172   // ceil(600000 / 512)

typedef __attribute__((ext_vector_type(8))) short short8;   // 8 bf16 (4 VGPRs)
typedef __attribute__((ext_vector_type(4))) float floatx4;  // MFMA C/D frag
typedef unsigned short ushort_t;

#define MFMA(a,b,c) __builtin_amdgcn_mfma_f32_16x16x32_bf16((a),(b),(c),0,0,0)

// Raw barrier WITHOUT vmcnt drain: __syncthreads makes the compiler emit
// s_waitcnt vmcnt(0) before s_barrier, draining cross-barrier prefetch.
// lgkmcnt(0) suffices for cross-wave LDS visibility.
__device__ __forceinline__ void bar_sync() {
    asm volatile("s_waitcnt lgkmcnt(0)" ::: "memory");
    __builtin_amdgcn_s_barrier();
    asm volatile("" ::: "memory");
}

__device__ __forceinline__ unsigned short f2bf(float f) {
    unsigned int u = __float_as_uint(f);
    u += 0x7fffu + ((u >> 16) & 1u);   // round-to-nearest-even
    return (unsigned short)(u >> 16);
}

__device__ __forceinline__ short8 pack8(const float4& a, const float4& b) {
    short8 r;
    r[0] = (short)f2bf(a.x); r[1] = (short)f2bf(a.y);
    r[2] = (short)f2bf(a.z); r[3] = (short)f2bf(a.w);
    r[4] = (short)f2bf(b.x); r[5] = (short)f2bf(b.y);
    r[6] = (short)f2bf(b.z); r[7] = (short)f2bf(b.w);
    return r;
}

// bf16 + bf16 -> bf16 (fp32 add internally)
__device__ __forceinline__ short8 addpack_bf(short8 a, short8 b) {
    short8 r;
    #pragma unroll
    for (int i = 0; i < 8; ++i) {
        const float fa = __uint_as_float(((unsigned int)(unsigned short)a[i]) << 16);
        const float fb = __uint_as_float(((unsigned int)(unsigned short)b[i]) << 16);
        r[i] = (short)f2bf(fa + fb);
    }
    return r;
}

__device__ __forceinline__ float mish_f(float v) {
    if (v > 30.0f) return v;
    float t = __expf(v);
    float z = 1.0f + t;
    float z2 = z * z;
    return v * (z2 - 1.0f) / (z2 + 1.0f);
}

// B-fragment of W (row-major [K][128] fp32) for col-tile ct, k-tile kt.
__device__ __forceinline__ short8 load_bfrag(const float* __restrict__ W,
                                             int ct, int kt, int lane) {
    const float* p = W + (size_t)(kt * 32 + (lane >> 4) * 8) * DIM + ct * 16 + (lane & 15);
    short8 r;
    #pragma unroll
    for (int j = 0; j < 8; ++j) r[j] = (short)f2bf(p[(size_t)j * DIM]);
    return r;
}

// MLP compute on a staged 32-row tile. 8 waves; wave w owns cols [16w,16w+16).
// s_in/s_h: XOR-granule swizzle (granule=16B, phys = g ^ (row&7)).
__device__ __forceinline__ void mlp_core(
    const ushort_t* __restrict__ s_in, ushort_t* __restrict__ s_h,
    const short8 (&w1f)[8], const short8 (&w2f)[4],
    float b1v, float b2v, float* __restrict__ out, int wave, int lane)
{
    const int r0 = lane & 15, q = lane >> 4, sw = lane & 7;

    floatx4 acc0 = {0.f,0.f,0.f,0.f}, acc1 = acc0;
    #pragma unroll
    for (int kt = 0; kt < 8; ++kt) {
        const int g = kt * 4 + q;
        short8 a0 = *(const short8*)&s_in[r0 * 256 + (g ^ sw) * 8];
        short8 a1 = *(const short8*)&s_in[(16 + r0) * 256 + (g ^ sw) * 8];
        acc0 = MFMA(a0, w1f[kt], acc0);
        acc1 = MFMA(a1, w1f[kt], acc1);
    }

    const int colg = wave * 2 + (r0 >> 3);   // 8-col granule index of our column
    const int bq   = r0 & 7;
    #pragma unroll
    for (int i = 0; i < 4; ++i) {
        int row = q * 4 + i;
        s_h[row * 128 + (colg ^ (row & 7)) * 8 + bq] = f2bf(mish_f(acc0[i] + b1v));
        row += 16;
        s_h[row * 128 + (colg ^ (row & 7)) * 8 + bq] = f2bf(mish_f(acc1[i] + b1v));
    }
    bar_sync();   // B2: s_h visible; in-flight global prefetch NOT drained

    floatx4 c0 = {0.f,0.f,0.f,0.f}, c1 = c0;
    #pragma unroll
    for (int kt = 0; kt < 4; ++kt) {
        const int g = kt * 4 + q;
        short8 a0 = *(const short8*)&s_h[r0 * 128 + (g ^ sw) * 8];
        short8 a1 = *(const short8*)&s_h[(16 + r0) * 128 + (g ^ sw) * 8];
        c0 = MFMA(a0, w2f[kt], c0);
        c1 = MFMA(a1, w2f[kt], c1);
    }

    const int col = wave * 16 + r0;
    #pragma unroll
    for (int i = 0; i < 4; ++i) {
        __builtin_nontemporal_store(c0[i] + b2v, &out[(size_t)(q * 4 + i) * DIM + col]);
        __builtin_nontemporal_store(c1[i] + b2v, &out[(size_t)(16 + q * 4 + i) * DIM + col]);
    }
}

// ---------------- utility / CSR construction ----------------

// fused: blocks [0,98) zero deg; blocks [98, 98+6250) convert x -> bf16
__global__ __launch_bounds__(256)
void zero_xbf_kernel(uint4* __restrict__ deg4, int n4,
                     const float* __restrict__ x, ushort_t* __restrict__ x_bf) {
    const int b = blockIdx.x;
    if (b < 98) {
        const int i = b * 256 + threadIdx.x;
        if (i < n4) deg4[i] = make_uint4(0u, 0u, 0u, 0u);
        return;
    }
    const int i = (b - 98) * 256 + threadIdx.x;   // 1.6M threads x 8 elems
    const float* p = x + (size_t)i * 8;
    *(short8*)&x_bf[(size_t)i * 8] = pack8(*(const float4*)p, *(const float4*)(p + 4));
}

__global__ __launch_bounds__(1024)
void scan_a(const int* __restrict__ deg, int* __restrict__ tmp, int* __restrict__ partials) {
    __shared__ int sm[1024];
    const int t = threadIdx.x;
    const int i = blockIdx.x * 1024 + t;
    const int v = (i < N_NODES) ? deg[i] : 0;
    sm[t] = v; __syncthreads();
    for (int d = 1; d < 1024; d <<= 1) {
        int u = (t >= d) ? sm[t - d] : 0; __syncthreads();
        sm[t] += u; __syncthreads();
    }
    if (i < N_NODES) tmp[i] = sm[t] - v;          // block-local exclusive
    if (t == 1023) partials[blockIdx.x] = sm[t];
}

// scan_c also does scan_b's job: each block redundantly scans the 98
// partials in LDS (trivial) -> one fewer dispatch + serialization point.
__global__ __launch_bounds__(1024)
void scan_c(const int* __restrict__ tmp, const int* __restrict__ partials,
            int* __restrict__ rowptr, int* __restrict__ cursor) {
    __shared__ int sm[128];
    const int t = threadIdx.x;
    if (t < 128) sm[t] = (t < 98) ? partials[t] : 0;
    __syncthreads();
    for (int d = 1; d < 128; d <<= 1) {
        int u = 0;
        if (t < 128 && t >= d) u = sm[t - d];
        __syncthreads();
        if (t < 128) sm[t] += u;
        __syncthreads();
    }
    const int poff = (blockIdx.x == 0) ? 0 : sm[blockIdx.x - 1];  // exclusive
    const int i = blockIdx.x * 1024 + t;
    if (i < N_NODES) {
        const int v = tmp[i] + poff;
        rowptr[i] = v; cursor[i] = v;
    }
    if (i == 0) rowptr[N_NODES] = N_EDGES;
}

__global__ __launch_bounds__(256)
void scatter_kernel(const int* __restrict__ dst_idx, int* __restrict__ cursor,
                    int* __restrict__ perm) {
    const int e = blockIdx.x * 256 + threadIdx.x;
    if (e < N_EDGES) {
        const int pos = atomicAdd(&cursor[dst_idx[e]], 1);
        perm[pos] = e;
    }
}

// ------- agg gather: 16-lane group per node, 4-deep row ILP, bf16 out -------
// Runs AFTER edge_kernel so its edge_attr gathers hit the L2/L3 residency the
// edge stream just established (nt e_out stores avoid evicting it).

__global__ __launch_bounds__(256)
void agg_kernel(const float* __restrict__ edge_attr, const int* __restrict__ rowptr,
                const int* __restrict__ perm, ushort_t* __restrict__ agg_bf) {
    const int g  = (blockIdx.x << 4) + (threadIdx.x >> 4);   // node id (16/block)
    const int ln = threadIdx.x & 15;                         // 16 lanes x 32B = row
    const int k0 = rowptr[g], k1 = rowptr[g + 1];
    float4 A0 = {0.f,0.f,0.f,0.f}, A1 = A0, B0 = A0, B1 = A0;
    int e0 = 0, e1 = 0, e2 = 0, e3 = 0;               // named regs (rule 20)
    if (k0 < k1)     e0 = perm[k0];
    if (k0 + 1 < k1) e1 = perm[k0 + 1];
    if (k0 + 2 < k1) e2 = perm[k0 + 2];
    if (k0 + 3 < k1) e3 = perm[k0 + 3];
    int k = k0;
    for (; k + 3 < k1; k += 4) {                      // 4 rows in flight
        const float* p0 = edge_attr + (size_t)e0 * DIM + ln * 8;
        const float* p1 = edge_attr + (size_t)e1 * DIM + ln * 8;
        const float* p2 = edge_attr + (size_t)e2 * DIM + ln * 8;
        const float* p3 = edge_attr + (size_t)e3 * DIM + ln * 8;
        const float4 a0 = *(const float4*)p0, a1 = *(const float4*)(p0 + 4);
        const float4 b0 = *(const float4*)p1, b1 = *(const float4*)(p1 + 4);
        const float4 c0 = *(const float4*)p2, c1 = *(const float4*)(p2 + 4);
        const float4 d0 = *(const float4*)p3, d1 = *(const float4*)(p3 + 4);
        if (k + 4 < k1) e0 = perm[k + 4];
        if (k + 5 < k1) e1 = perm[k + 5];
        if (k + 6 < k1) e2 = perm[k + 6];
        if (k + 7 < k1) e3 = perm[k + 7];
        A0.x += a0.x + c0.x; A0.y += a0.y + c0.y; A0.z += a0.z + c0.z; A0.w += a0.w + c0.w;
        A1.x += a1.x + c1.x; A1.y += a1.y + c1.y; A1.z += a1.z + c1.z; A1.w += a1.w + c1.w;
        B0.x += b0.x + d0.x; B0.y += b0.y + d0.y; B0.z += b0.z + d0.z; B0.w += b0.w + d0.w;
        B1.x += b1.x + d1.x; B1.y += b1.y + d1.y; B1.z += b1.z + d1.z; B1.w += b1.w + d1.w;
    }
    const int rem = k1 - k;                           // 0..3 tail rows = e0,e1,e2
    if (rem > 0) {
        const float* p = edge_attr + (size_t)e0 * DIM + ln * 8;
        const float4 v0 = *(const float4*)p, v1 = *(const float4*)(p + 4);
        A0.x += v0.x; A0.y += v0.y; A0.z += v0.z; A0.w += v0.w;
        A1.x += v1.x; A1.y += v1.y; A1.z += v1.z; A1.w += v1.w;
    }
    if (rem > 1) {
        const float* p = edge_attr + (size_t)e1 * DIM + ln * 8;
        const float4 v0 = *(const float4*)p, v1 = *(const float4*)(p + 4);
        B0.x += v0.x; B0.y += v0.y; B0.z += v0.z; B0.w += v0.w;
        B1.x += v1.x; B1.y += v1.y; B1.z += v1.z; B1.w += v1.w;
    }
    if (rem > 2) {
        const float* p = edge_attr + (size_t)e2 * DIM + ln * 8;
        const float4 v0 = *(const float4*)p, v1 = *(const float4*)(p + 4);
        A0.x += v0.x; A0.y += v0.y; A0.z += v0.z; A0.w += v0.w;
        A1.x += v1.x; A1.y += v1.y; A1.z += v1.z; A1.w += v1.w;
    }
    A0.x += B0.x; A0.y += B0.y; A0.z += B0.z; A0.w += B0.w;
    A1.x += B1.x; A1.y += B1.y; A1.z += B1.z; A1.w += B1.w;
    *(short8*)&agg_bf[(size_t)g * DIM + ln * 8] = pack8(A0, A1);
}

// ---------------- main MLP kernels (512 threads, 8 waves) ----------------
// VGPR discipline (measured): <=64 VGPR -> ~40% occ (fast); 65+ -> 23% occ
// (+45% time, r8/r10/r14); forced-32 -> spill disaster (r9). 24KB LDS; the
// round-12/15 structure is the measured optimum of this landscape.
// hist is fused in as blocks [EDGE_BLOCKS, EDGE_BLOCKS+HIST_BLOCKS):
// independent of the edge path (dst_idx -> deg; deg pre-zeroed dispatch 1),
// its short blocks backfill CU slots as edge blocks retire (r13 precedent:
// block-split second path did not perturb edge's 64-VGPR allocation).

__global__ __launch_bounds__(512)
void edge_hist_kernel(const ushort_t* __restrict__ x_bf,
                      const float* __restrict__ edge_attr,
                      const int* __restrict__ src_idx, const int* __restrict__ dst_idx,
                      const float* __restrict__ W1, const float* __restrict__ b1,
                      const float* __restrict__ W2, const float* __restrict__ b2,
                      float* __restrict__ e_out, int* __restrict__ deg)
{
    __shared__ ushort_t s_in[32 * 256];   // 16 KB (edge path only)
    __shared__ ushort_t s_h[32 * 128];    // 8 KB
    const int tid = threadIdx.x;

    if (blockIdx.x >= EDGE_BLOCKS) {
        // ---- hist path: 512 threads/block, 1 edge each ----
        const int e = (blockIdx.x - EDGE_BLOCKS) * 512 + tid;
        if (e < N_EDGES) atomicAdd(&deg[dst_idx[e]], 1);
        return;
    }

    // ---- edge path (round-12/15 structure, grid EDGE_BLOCKS) ----
    const int wave = tid >> 6, lane = tid & 63;

    short8 w1f[8], w2f[4];
    const float b1v = b1[wave * 16 + (lane & 15)];
    const float b2v = b2[wave * 16 + (lane & 15)];
    #pragma unroll
    for (int kt = 0; kt < 8; ++kt) w1f[kt] = load_bfrag(W1, wave, kt, lane);
    #pragma unroll
    for (int kt = 0; kt < 4; ++kt) w2f[kt] = load_bfrag(W2, wave, kt, lane);

    const int r = tid >> 4, gq = tid & 15, swr = r & 7;
    ushort_t* w_ea = &s_in[r * 256 + (gq ^ swr) * 8];
    ushort_t* w_x  = &s_in[r * 256 + ((16 + gq) ^ swr) * 8];

    const int ntiles = N_EDGES / 32;   // 18750
    int t = blockIdx.x;
    float4 ea0, ea1;
    short8 xsb, xdb;
    if (t < ntiles) {                                    // prologue loads (tile t)
        const int k = t * 32 + r;
        const int s = src_idx[k], d = dst_idx[k];
        const float* pe = edge_attr + (size_t)k * DIM + gq * 8;
        ea0 = *(const float4*)pe; ea1 = *(const float4*)(pe + 4);
        xsb = *(const short8*)&x_bf[(size_t)s * DIM + gq * 8];
        xdb = *(const short8*)&x_bf[(size_t)d * DIM + gq * 8];
    }
    for (; t < ntiles; t += EDGE_BLOCKS) {
        // stage current tile: regs -> LDS (prev iter's s_in readers done pre-B2)
        *(short8*)w_ea = pack8(ea0, ea1);
        *(short8*)w_x  = addpack_bf(xsb, xdb);

        const int tn = t + EDGE_BLOCKS;
        const bool more = tn < ntiles;                   // block-uniform
        int sN = 0, dN = 0;
        if (more) {
            // ea(t+G): sequential HBM stream, no index dep -> issue PRE-B1,
            // gets the entire tile (~900+ cyc) of coverage before consumption
            const float* pe = edge_attr + (size_t)(tn * 32 + r) * DIM + gq * 8;
            ea0 = *(const float4*)pe; ea1 = *(const float4*)(pe + 4);
            const int k = tn * 32 + r;
            sN = src_idx[k]; dN = dst_idx[k];            // idx also pre-B1
        }
        bar_sync();                                      // B1: staging visible
        if (more) {                                      // L3-hot gathers post-B1
            xsb = *(const short8*)&x_bf[(size_t)sN * DIM + gq * 8];
            xdb = *(const short8*)&x_bf[(size_t)dN * DIM + gq * 8];
        }
        mlp_core(s_in, s_h, w1f, w2f, b1v, b2v,
                 e_out + (size_t)t * 32 * DIM, wave, lane);
    }
}

__global__ __launch_bounds__(512)
void node_kernel(const float* __restrict__ x, const ushort_t* __restrict__ agg_bf,
                 const float* __restrict__ W1, const float* __restrict__ b1,
                 const float* __restrict__ W2, const float* __restrict__ b2,
                 float* __restrict__ x_out)
{
    __shared__ ushort_t s_in[32 * 256];
    __shared__ ushort_t s_h[32 * 128];
    const int tid = threadIdx.x, wave = tid >> 6, lane = tid & 63;

    short8 w1f[8], w2f[4];
    const float b1v = b1[wave * 16 + (lane & 15)];
    const float b2v = b2[wave * 16 + (lane & 15)];
    #pragma unroll
    for (int kt = 0; kt < 8; ++kt) w1f[kt] = load_bfrag(W1, wave, kt, lane);
    #pragma unroll
    for (int kt = 0; kt < 4; ++kt) w2f[kt] = load_bfrag(W2, wave, kt, lane);

    const int r = tid >> 4, gq = tid & 15, swr = r & 7;
    ushort_t* w_xp = &s_in[r * 256 + (gq ^ swr) * 8];
    ushort_t* w_ag = &s_in[r * 256 + ((16 + gq) ^ swr) * 8];

    const int ntiles = N_NODES / 32;   // 3125
    int t = blockIdx.x;
    float4 xv0, xv1;
    short8 ag;
    if (t < ntiles) {
        const float* px = x + (size_t)(t * 32 + r) * DIM + gq * 8;
        xv0 = *(const float4*)px; xv1 = *(const float4*)(px + 4);
        ag  = *(const short8*)&agg_bf[(size_t)(t * 32 + r) * DIM + gq * 8];
    }
    for (; t < ntiles; t += gridDim.x) {
        *(short8*)w_xp = pack8(xv0, xv1);
        *(short8*)w_ag = ag;
        const int tn = t + gridDim.x;
        if (tn < ntiles) {                              // both streams sequential:
            const float* px = x + (size_t)(tn * 32 + r) * DIM + gq * 8;   // issue
            xv0 = *(const float4*)px; xv1 = *(const float4*)(px + 4);     // PRE-B1
            ag  = *(const short8*)&agg_bf[(size_t)(tn * 32 + r) * DIM + gq * 8];
        }
        bar_sync();                                     // B1
        mlp_core(s_in, s_h, w1f, w2f, b1v, b2v,
                 x_out + (size_t)t * 32 * DIM, wave, lane);
    }
}

extern "C" void kernel_launch(void* const* d_in, const int* in_sizes, int n_in,
                              void* d_out, int out_size, void* d_ws, size_t ws_size,
                              hipStream_t stream)
{
    const float* x         = (const float*)d_in[0];
    const float* edge_attr = (const float*)d_in[1];
    const int*   ei        = (const int*)d_in[2];   // [2, E]: src row then dst row
    const float* eW1 = (const float*)d_in[3];
    const float* eb1 = (const float*)d_in[4];
    const float* eW2 = (const float*)d_in[5];
    const float* eb2 = (const float*)d_in[6];
    const float* nW1 = (const float*)d_in[7];
    const float* nb1 = (const float*)d_in[8];
    const float* nW2 = (const float*)d_in[9];
    const float* nb2 = (const float*)d_in[10];

    float* out   = (float*)d_out;
    float* x_out = out;                             // [N, 128]
    float* e_out = out + (size_t)N_NODES * DIM;     // [E, 128]

    const int* src_idx = ei;
    const int* dst_idx = ei + N_EDGES;

    // workspace (ints): deg | tmp | rowptr | cursor | perm | partials | agg_bf
    int* wsi      = (int*)d_ws;
    int* deg      = wsi;                   // 100352
    int* tmp      = wsi + 100352;          // 100352
    int* rowptr   = wsi + 200704;          // 100352 (N+1 used)
    int* cursor   = wsi + 301056;          // 100352
    int* perm     = wsi + 401408;          // 600000
    int* partials = wsi + 1001408;         // 128
    ushort_t* agg_bf = (ushort_t*)(wsi + 1001536);  // 12.8M bf16 = 25.6 MB

    // x_bf lives in the x_out output region (25.6 of 51.2 MB): read only by
    // edge_hist_kernel, which runs BEFORE node_kernel overwrites x_out.
    ushort_t* x_bf = (ushort_t*)x_out;

    const int egrid = (N_EDGES + 255) / 256;

    // ORDER: edge (streams all of edge_attr through L2/L3) runs BEFORE the
    // CSR chain + agg; agg's gathered re-read of edge_attr hits that cache
    // residency (r13/r16 verified). hist rides inside the edge dispatch
    // (independent outputs; deg pre-zeroed in dispatch 1).
    zero_xbf_kernel<<<dim3(98 + 6250), dim3(256), 0, stream>>>(
        (uint4*)deg, 25088, x, x_bf);

    edge_hist_kernel<<<dim3(EDGE_BLOCKS + HIST_BLOCKS), dim3(512), 0, stream>>>(
        x_bf, edge_attr, src_idx, dst_idx, eW1, eb1, eW2, eb2, e_out, deg);

    scan_a        <<<dim3(98),    dim3(1024), 0, stream>>>(deg, tmp, partials);
    scan_c        <<<dim3(98),    dim3(1024), 0, stream>>>(tmp, partials, rowptr, cursor);
    scatter_kernel<<<dim3(egrid), dim3(256),  0, stream>>>(dst_idx, cursor, perm);

    agg_kernel<<<dim3(6250), dim3(256), 0, stream>>>(edge_attr, rowptr, perm, agg_bf);

    node_kernel<<<dim3(2048), dim3(512), 0, stream>>>(
        x, agg_bf, nW1, nb1, nW2, nb2, x_out);
}

// Round 18
// 327.957 us; speedup vs baseline: 1.3623x; 1.0137x over previous
//
#include <hip/hip_runtime.h>

#define N_NODES 100000
#define N_EDGES 600000
#define DIM 128

#define EDGE_BLOCKS 2048
#define HIST_BLOCKS 1172   // ceil(600000 / 512)

typedef __attribute__((ext_vector_type(8))) short short8;   // 8 bf16 (4 VGPRs)
typedef __attribute__((ext_vector_type(4))) float floatx4;  // MFMA C/D frag
typedef unsigned short ushort_t;

#define MFMA(a,b,c) __builtin_amdgcn_mfma_f32_16x16x32_bf16((a),(b),(c),0,0,0)

// Raw barrier WITHOUT vmcnt drain: __syncthreads makes the compiler emit
// s_waitcnt vmcnt(0) before s_barrier, draining cross-barrier prefetch.
// lgkmcnt(0) suffices for cross-wave LDS visibility.
__device__ __forceinline__ void bar_sync() {
    asm volatile("s_waitcnt lgkmcnt(0)" ::: "memory");
    __builtin_amdgcn_s_barrier();
    asm volatile("" ::: "memory");
}

// HW packed f32->bf16 (RNE): 2 values in ONE VALU op vs ~10 for bit-trick
// rounding. No builtin on gfx950 (m240/T12) -> inline asm. Non-volatile so
// the scheduler can move/CSE it.
__device__ __forceinline__ unsigned int cvt_pk_bf16(float lo, float hi) {
    unsigned int r;
    asm("v_cvt_pk_bf16_f32 %0, %1, %2" : "=v"(r) : "v"(lo), "v"(hi));
    return r;
}

__device__ __forceinline__ unsigned short f2bf(float f) {   // setup paths only
    unsigned int u = __float_as_uint(f);
    u += 0x7fffu + ((u >> 16) & 1u);   // round-to-nearest-even
    return (unsigned short)(u >> 16);
}

__device__ __forceinline__ short8 pack8(const float4& a, const float4& b) {
    union { unsigned int u[4]; short8 s; } c;
    c.u[0] = cvt_pk_bf16(a.x, a.y);
    c.u[1] = cvt_pk_bf16(a.z, a.w);
    c.u[2] = cvt_pk_bf16(b.x, b.y);
    c.u[3] = cvt_pk_bf16(b.z, b.w);
    return c.s;
}

// bf16 + bf16 -> bf16 (fp32 add, cvt_pk repack)
__device__ __forceinline__ short8 addpack_bf(short8 a, short8 b) {
    union { unsigned int u[4]; short8 s; } c;
    #pragma unroll
    for (int i = 0; i < 4; ++i) {
        const float lo = __uint_as_float(((unsigned int)(unsigned short)a[2*i]) << 16)
                       + __uint_as_float(((unsigned int)(unsigned short)b[2*i]) << 16);
        const float hi = __uint_as_float(((unsigned int)(unsigned short)a[2*i+1]) << 16)
                       + __uint_as_float(((unsigned int)(unsigned short)b[2*i+1]) << 16);
        c.u[i] = cvt_pk_bf16(lo, hi);
    }
    return c.s;
}

__device__ __forceinline__ float mish_f(float v) {
    if (v > 30.0f) return v;
    float t = __expf(v);
    float z = 1.0f + t;
    float z2 = z * z;
    return v * (z2 - 1.0f) / (z2 + 1.0f);
}

// B-fragment of W (row-major [K][128] fp32) for col-tile ct, k-tile kt.
__device__ __forceinline__ short8 load_bfrag(const float* __restrict__ W,
                                             int ct, int kt, int lane) {
    const float* p = W + (size_t)(kt * 32 + (lane >> 4) * 8) * DIM + ct * 16 + (lane & 15);
    short8 r;
    #pragma unroll
    for (int j = 0; j < 8; ++j) r[j] = (short)f2bf(p[(size_t)j * DIM]);
    return r;
}

// MLP compute on a staged 32-row tile. 8 waves; wave w owns cols [16w,16w+16).
// s_in/s_h: XOR-granule swizzle (granule=16B, phys = g ^ (row&7)).
__device__ __forceinline__ void mlp_core(
    const ushort_t* __restrict__ s_in, ushort_t* __restrict__ s_h,
    const short8 (&w1f)[8], const short8 (&w2f)[4],
    float b1v, float b2v, float* __restrict__ out, int wave, int lane)
{
    const int r0 = lane & 15, q = lane >> 4, sw = lane & 7;

    floatx4 acc0 = {0.f,0.f,0.f,0.f}, acc1 = acc0;
    #pragma unroll
    for (int kt = 0; kt < 8; ++kt) {
        const int g = kt * 4 + q;
        short8 a0 = *(const short8*)&s_in[r0 * 256 + (g ^ sw) * 8];
        short8 a1 = *(const short8*)&s_in[(16 + r0) * 256 + (g ^ sw) * 8];
        acc0 = MFMA(a0, w1f[kt], acc0);
        acc1 = MFMA(a1, w1f[kt], acc1);
    }

    const int colg = wave * 2 + (r0 >> 3);   // 8-col granule index of our column
    const int bq   = r0 & 7;
    #pragma unroll
    for (int i = 0; i < 4; ++i) {
        const int row = q * 4 + i;           // (row+16)&7 == row&7 -> same swizzle
        const unsigned int pk =
            cvt_pk_bf16(mish_f(acc0[i] + b1v), mish_f(acc1[i] + b1v));
        const int off = (colg ^ (row & 7)) * 8 + bq;
        s_h[row * 128 + off]        = (ushort_t)pk;
        s_h[(row + 16) * 128 + off] = (ushort_t)(pk >> 16);
    }
    bar_sync();   // B2: s_h visible; in-flight global prefetch NOT drained

    floatx4 c0 = {0.f,0.f,0.f,0.f}, c1 = c0;
    #pragma unroll
    for (int kt = 0; kt < 4; ++kt) {
        const int g = kt * 4 + q;
        short8 a0 = *(const short8*)&s_h[r0 * 128 + (g ^ sw) * 8];
        short8 a1 = *(const short8*)&s_h[(16 + r0) * 128 + (g ^ sw) * 8];
        c0 = MFMA(a0, w2f[kt], c0);
        c1 = MFMA(a1, w2f[kt], c1);
    }

    const int col = wave * 16 + r0;
    #pragma unroll
    for (int i = 0; i < 4; ++i) {
        __builtin_nontemporal_store(c0[i] + b2v, &out[(size_t)(q * 4 + i) * DIM + col]);
        __builtin_nontemporal_store(c1[i] + b2v, &out[(size_t)(16 + q * 4 + i) * DIM + col]);
    }
}

// ---------------- utility / CSR construction ----------------

// fused: blocks [0,98) zero deg; blocks [98, 98+6250) convert x -> bf16
__global__ __launch_bounds__(256)
void zero_xbf_kernel(uint4* __restrict__ deg4, int n4,
                     const float* __restrict__ x, ushort_t* __restrict__ x_bf) {
    const int b = blockIdx.x;
    if (b < 98) {
        const int i = b * 256 + threadIdx.x;
        if (i < n4) deg4[i] = make_uint4(0u, 0u, 0u, 0u);
        return;
    }
    const int i = (b - 98) * 256 + threadIdx.x;   // 1.6M threads x 8 elems
    const float* p = x + (size_t)i * 8;
    *(short8*)&x_bf[(size_t)i * 8] = pack8(*(const float4*)p, *(const float4*)(p + 4));
}

__global__ __launch_bounds__(1024)
void scan_a(const int* __restrict__ deg, int* __restrict__ tmp, int* __restrict__ partials) {
    __shared__ int sm[1024];
    const int t = threadIdx.x;
    const int i = blockIdx.x * 1024 + t;
    const int v = (i < N_NODES) ? deg[i] : 0;
    sm[t] = v; __syncthreads();
    for (int d = 1; d < 1024; d <<= 1) {
        int u = (t >= d) ? sm[t - d] : 0; __syncthreads();
        sm[t] += u; __syncthreads();
    }
    if (i < N_NODES) tmp[i] = sm[t] - v;          // block-local exclusive
    if (t == 1023) partials[blockIdx.x] = sm[t];
}

// scan_c also does scan_b's job: each block redundantly scans the 98
// partials in LDS (trivial) -> one fewer dispatch + serialization point.
__global__ __launch_bounds__(1024)
void scan_c(const int* __restrict__ tmp, const int* __restrict__ partials,
            int* __restrict__ rowptr, int* __restrict__ cursor) {
    __shared__ int sm[128];
    const int t = threadIdx.x;
    if (t < 128) sm[t] = (t < 98) ? partials[t] : 0;
    __syncthreads();
    for (int d = 1; d < 128; d <<= 1) {
        int u = 0;
        if (t < 128 && t >= d) u = sm[t - d];
        __syncthreads();
        if (t < 128) sm[t] += u;
        __syncthreads();
    }
    const int poff = (blockIdx.x == 0) ? 0 : sm[blockIdx.x - 1];  // exclusive
    const int i = blockIdx.x * 1024 + t;
    if (i < N_NODES) {
        const int v = tmp[i] + poff;
        rowptr[i] = v; cursor[i] = v;
    }
    if (i == 0) rowptr[N_NODES] = N_EDGES;
}

__global__ __launch_bounds__(256)
void scatter_kernel(const int* __restrict__ dst_idx, int* __restrict__ cursor,
                    int* __restrict__ perm) {
    const int e = blockIdx.x * 256 + threadIdx.x;
    if (e < N_EDGES) {
        const int pos = atomicAdd(&cursor[dst_idx[e]], 1);
        perm[pos] = e;
    }
}

// ------- agg gather: 16-lane group per node, 4-deep row ILP, bf16 out -------
// Runs AFTER edge_kernel so its edge_attr gathers hit the L2/L3 residency the
// edge stream just established (nt e_out stores avoid evicting it).

__global__ __launch_bounds__(256)
void agg_kernel(const float* __restrict__ edge_attr, const int* __restrict__ rowptr,
                const int* __restrict__ perm, ushort_t* __restrict__ agg_bf) {
    const int g  = (blockIdx.x << 4) + (threadIdx.x >> 4);   // node id (16/block)
    const int ln = threadIdx.x & 15;                         // 16 lanes x 32B = row
    const int k0 = rowptr[g], k1 = rowptr[g + 1];
    float4 A0 = {0.f,0.f,0.f,0.f}, A1 = A0, B0 = A0, B1 = A0;
    int e0 = 0, e1 = 0, e2 = 0, e3 = 0;               // named regs (rule 20)
    if (k0 < k1)     e0 = perm[k0];
    if (k0 + 1 < k1) e1 = perm[k0 + 1];
    if (k0 + 2 < k1) e2 = perm[k0 + 2];
    if (k0 + 3 < k1) e3 = perm[k0 + 3];
    int k = k0;
    for (; k + 3 < k1; k += 4) {                      // 4 rows in flight
        const float* p0 = edge_attr + (size_t)e0 * DIM + ln * 8;
        const float* p1 = edge_attr + (size_t)e1 * DIM + ln * 8;
        const float* p2 = edge_attr + (size_t)e2 * DIM + ln * 8;
        const float* p3 = edge_attr + (size_t)e3 * DIM + ln * 8;
        const float4 a0 = *(const float4*)p0, a1 = *(const float4*)(p0 + 4);
        const float4 b0 = *(const float4*)p1, b1 = *(const float4*)(p1 + 4);
        const float4 c0 = *(const float4*)p2, c1 = *(const float4*)(p2 + 4);
        const float4 d0 = *(const float4*)p3, d1 = *(const float4*)(p3 + 4);
        if (k + 4 < k1) e0 = perm[k + 4];
        if (k + 5 < k1) e1 = perm[k + 5];
        if (k + 6 < k1) e2 = perm[k + 6];
        if (k + 7 < k1) e3 = perm[k + 7];
        A0.x += a0.x + c0.x; A0.y += a0.y + c0.y; A0.z += a0.z + c0.z; A0.w += a0.w + c0.w;
        A1.x += a1.x + c1.x; A1.y += a1.y + c1.y; A1.z += a1.z + c1.z; A1.w += a1.w + c1.w;
        B0.x += b0.x + d0.x; B0.y += b0.y + d0.y; B0.z += b0.z + d0.z; B0.w += b0.w + d0.w;
        B1.x += b1.x + d1.x; B1.y += b1.y + d1.y; B1.z += b1.z + d1.z; B1.w += b1.w + d1.w;
    }
    const int rem = k1 - k;                           // 0..3 tail rows = e0,e1,e2
    if (rem > 0) {
        const float* p = edge_attr + (size_t)e0 * DIM + ln * 8;
        const float4 v0 = *(const float4*)p, v1 = *(const float4*)(p + 4);
        A0.x += v0.x; A0.y += v0.y; A0.z += v0.z; A0.w += v0.w;
        A1.x += v1.x; A1.y += v1.y; A1.z += v1.z; A1.w += v1.w;
    }
    if (rem > 1) {
        const float* p = edge_attr + (size_t)e1 * DIM + ln * 8;
        const float4 v0 = *(const float4*)p, v1 = *(const float4*)(p + 4);
        B0.x += v0.x; B0.y += v0.y; B0.z += v0.z; B0.w += v0.w;
        B1.x += v1.x; B1.y += v1.y; B1.z += v1.z; B1.w += v1.w;
    }
    if (rem > 2) {
        const float* p = edge_attr + (size_t)e2 * DIM + ln * 8;
        const float4 v0 = *(const float4*)p, v1 = *(const float4*)(p + 4);
        A0.x += v0.x; A0.y += v0.y; A0.z += v0.z; A0.w += v0.w;
        A1.x += v1.x; A1.y += v1.y; A1.z += v1.z; A1.w += v1.w;
    }
    A0.x += B0.x; A0.y += B0.y; A0.z += B0.z; A0.w += B0.w;
    A1.x += B1.x; A1.y += B1.y; A1.z += B1.z; A1.w += B1.w;
    *(short8*)&agg_bf[(size_t)g * DIM + ln * 8] = pack8(A0, A1);
}

// ---------------- main MLP kernels (512 threads, 8 waves) ----------------
// VGPR discipline (measured): <=64 VGPR -> ~40% occ (fast); 65+ -> 23% occ
// (+45% time, r8/r10/r14); forced-32 -> spill disaster (r9). 24KB LDS; the
// round-12/15 structure is the measured optimum of this landscape.
// hist rides as blocks [EDGE_BLOCKS, EDGE_BLOCKS+HIST_BLOCKS) (r17: +0 VGPR,
// occupancy 42%, FETCH down 447->296MB).

__global__ __launch_bounds__(512)
void edge_hist_kernel(const ushort_t* __restrict__ x_bf,
                      const float* __restrict__ edge_attr,
                      const int* __restrict__ src_idx, const int* __restrict__ dst_idx,
                      const float* __restrict__ W1, const float* __restrict__ b1,
                      const float* __restrict__ W2, const float* __restrict__ b2,
                      float* __restrict__ e_out, int* __restrict__ deg)
{
    __shared__ ushort_t s_in[32 * 256];   // 16 KB (edge path only)
    __shared__ ushort_t s_h[32 * 128];    // 8 KB
    const int tid = threadIdx.x;

    if (blockIdx.x >= EDGE_BLOCKS) {
        // ---- hist path: 512 threads/block, 1 edge each ----
        const int e = (blockIdx.x - EDGE_BLOCKS) * 512 + tid;
        if (e < N_EDGES) atomicAdd(&deg[dst_idx[e]], 1);
        return;
    }

    // ---- edge path (round-12/15 structure, grid EDGE_BLOCKS) ----
    const int wave = tid >> 6, lane = tid & 63;

    short8 w1f[8], w2f[4];
    const float b1v = b1[wave * 16 + (lane & 15)];
    const float b2v = b2[wave * 16 + (lane & 15)];
    #pragma unroll
    for (int kt = 0; kt < 8; ++kt) w1f[kt] = load_bfrag(W1, wave, kt, lane);
    #pragma unroll
    for (int kt = 0; kt < 4; ++kt) w2f[kt] = load_bfrag(W2, wave, kt, lane);

    const int r = tid >> 4, gq = tid & 15, swr = r & 7;
    ushort_t* w_ea = &s_in[r * 256 + (gq ^ swr) * 8];
    ushort_t* w_x  = &s_in[r * 256 + ((16 + gq) ^ swr) * 8];

    const int ntiles = N_EDGES / 32;   // 18750
    int t = blockIdx.x;
    float4 ea0, ea1;
    short8 xsb, xdb;
    if (t < ntiles) {                                    // prologue loads (tile t)
        const int k = t * 32 + r;
        const int s = src_idx[k], d = dst_idx[k];
        const float* pe = edge_attr + (size_t)k * DIM + gq * 8;
        ea0 = *(const float4*)pe; ea1 = *(const float4*)(pe + 4);
        xsb = *(const short8*)&x_bf[(size_t)s * DIM + gq * 8];
        xdb = *(const short8*)&x_bf[(size_t)d * DIM + gq * 8];
    }
    for (; t < ntiles; t += EDGE_BLOCKS) {
        // stage current tile: regs -> LDS (prev iter's s_in readers done pre-B2)
        *(short8*)w_ea = pack8(ea0, ea1);
        *(short8*)w_x  = addpack_bf(xsb, xdb);

        const int tn = t + EDGE_BLOCKS;
        const bool more = tn < ntiles;                   // block-uniform
        int sN = 0, dN = 0;
        if (more) {
            // ea(t+G): sequential HBM stream, no index dep -> issue PRE-B1,
            // gets the entire tile (~900+ cyc) of coverage before consumption
            const float* pe = edge_attr + (size_t)(tn * 32 + r) * DIM + gq * 8;
            ea0 = *(const float4*)pe; ea1 = *(const float4*)(pe + 4);
            const int k = tn * 32 + r;
            sN = src_idx[k]; dN = dst_idx[k];            // idx also pre-B1
        }
        bar_sync();                                      // B1: staging visible
        if (more) {                                      // L3-hot gathers post-B1
            xsb = *(const short8*)&x_bf[(size_t)sN * DIM + gq * 8];
            xdb = *(const short8*)&x_bf[(size_t)dN * DIM + gq * 8];
        }
        mlp_core(s_in, s_h, w1f, w2f, b1v, b2v,
                 e_out + (size_t)t * 32 * DIM, wave, lane);
    }
}

__global__ __launch_bounds__(512)
void node_kernel(const float* __restrict__ x, const ushort_t* __restrict__ agg_bf,
                 const float* __restrict__ W1, const float* __restrict__ b1,
                 const float* __restrict__ W2, const float* __restrict__ b2,
                 float* __restrict__ x_out)
{
    __shared__ ushort_t s_in[32 * 256];
    __shared__ ushort_t s_h[32 * 128];
    const int tid = threadIdx.x, wave = tid >> 6, lane = tid & 63;

    short8 w1f[8], w2f[4];
    const float b1v = b1[wave * 16 + (lane & 15)];
    const float b2v = b2[wave * 16 + (lane & 15)];
    #pragma unroll
    for (int kt = 0; kt < 8; ++kt) w1f[kt] = load_bfrag(W1, wave, kt, lane);
    #pragma unroll
    for (int kt = 0; kt < 4; ++kt) w2f[kt] = load_bfrag(W2, wave, kt, lane);

    const int r = tid >> 4, gq = tid & 15, swr = r & 7;
    ushort_t* w_xp = &s_in[r * 256 + (gq ^ swr) * 8];
    ushort_t* w_ag = &s_in[r * 256 + ((16 + gq) ^ swr) * 8];

    const int ntiles = N_NODES / 32;   // 3125
    int t = blockIdx.x;
    float4 xv0, xv1;
    short8 ag;
    if (t < ntiles) {
        const float* px = x + (size_t)(t * 32 + r) * DIM + gq * 8;
        xv0 = *(const float4*)px; xv1 = *(const float4*)(px + 4);
        ag  = *(const short8*)&agg_bf[(size_t)(t * 32 + r) * DIM + gq * 8];
    }
    for (; t < ntiles; t += gridDim.x) {
        *(short8*)w_xp = pack8(xv0, xv1);
        *(short8*)w_ag = ag;
        const int tn = t + gridDim.x;
        if (tn < ntiles) {                              // both streams sequential:
            const float* px = x + (size_t)(tn * 32 + r) * DIM + gq * 8;   // issue
            xv0 = *(const float4*)px; xv1 = *(const float4*)(px + 4);     // PRE-B1
            ag  = *(const short8*)&agg_bf[(size_t)(tn * 32 + r) * DIM + gq * 8];
        }
        bar_sync();                                     // B1
        mlp_core(s_in, s_h, w1f, w2f, b1v, b2v,
                 x_out + (size_t)t * 32 * DIM, wave, lane);
    }
}

extern "C" void kernel_launch(void* const* d_in, const int* in_sizes, int n_in,
                              void* d_out, int out_size, void* d_ws, size_t ws_size,
                              hipStream_t stream)
{
    const float* x         = (const float*)d_in[0];
    const float* edge_attr = (const float*)d_in[1];
    const int*   ei        = (const int*)d_in[2];   // [2, E]: src row then dst row
    const float* eW1 = (const float*)d_in[3];
    const float* eb1 = (const float*)d_in[4];
    const float* eW2 = (const float*)d_in[5];
    const float* eb2 = (const float*)d_in[6];
    const float* nW1 = (const float*)d_in[7];
    const float* nb1 = (const float*)d_in[8];
    const float* nW2 = (const float*)d_in[9];
    const float* nb2 = (const float*)d_in[10];

    float* out   = (float*)d_out;
    float* x_out = out;                             // [N, 128]
    float* e_out = out + (size_t)N_NODES * DIM;     // [E, 128]

    const int* src_idx = ei;
    const int* dst_idx = ei + N_EDGES;

    // workspace (ints): deg | tmp | rowptr | cursor | perm | partials | agg_bf
    int* wsi      = (int*)d_ws;
    int* deg      = wsi;                   // 100352
    int* tmp      = wsi + 100352;          // 100352
    int* rowptr   = wsi + 200704;          // 100352 (N+1 used)
    int* cursor   = wsi + 301056;          // 100352
    int* perm     = wsi + 401408;          // 600000
    int* partials = wsi + 1001408;         // 128
    ushort_t* agg_bf = (ushort_t*)(wsi + 1001536);  // 12.8M bf16 = 25.6 MB

    // x_bf lives in the x_out output region (25.6 of 51.2 MB): read only by
    // edge_hist_kernel, which runs BEFORE node_kernel overwrites x_out.
    ushort_t* x_bf = (ushort_t*)x_out;

    const int egrid = (N_EDGES + 255) / 256;

    // ORDER: edge (streams all of edge_attr through L2/L3) runs BEFORE the
    // CSR chain + agg; agg's gathered re-read of edge_attr hits that cache
    // residency (r13/r16 verified). hist rides inside the edge dispatch
    // (independent outputs; deg pre-zeroed in dispatch 1).
    zero_xbf_kernel<<<dim3(98 + 6250), dim3(256), 0, stream>>>(
        (uint4*)deg, 25088, x, x_bf);

    edge_hist_kernel<<<dim3(EDGE_BLOCKS + HIST_BLOCKS), dim3(512), 0, stream>>>(
        x_bf, edge_attr, src_idx, dst_idx, eW1, eb1, eW2, eb2, e_out, deg);

    scan_a        <<<dim3(98),    dim3(1024), 0, stream>>>(deg, tmp, partials);
    scan_c        <<<dim3(98),    dim3(1024), 0, stream>>>(tmp, partials, rowptr, cursor);
    scatter_kernel<<<dim3(egrid), dim3(256),  0, stream>>>(dst_idx, cursor, perm);

    agg_kernel<<<dim3(6250), dim3(256), 0, stream>>>(edge_attr, rowptr, perm, agg_bf);

    node_kernel<<<dim3(2048), dim3(512), 0, stream>>>(
        x, agg_bf, nW1, nb1, nW2, nb2, x_out);
}